// Round 1
// baseline (22230.856 us; speedup 1.0000x reference)
//
#include <hip/hip_runtime.h>
#include <stdint.h>

#define N_ANCH   106392
#define PRE_NMS  6000
#define POST_NMS 1000
#define POOL_CAP 8192
#define SORT_N   8192
#define NMS_BLKS 94   // 94*64 = 6016 >= 6000

static __device__ const int    LV_H[5]      = {128, 64, 32, 16, 8};
static __device__ const int    LV_W[5]      = {208, 104, 52, 26, 13};
static __device__ const int    LV_STRIDE[5] = {4, 8, 16, 32, 64};
static __device__ const int    LV_PIX[5]    = {26624, 6656, 1664, 416, 104};
static __device__ const int    LV_TILE0[6]  = {0, 416, 520, 546, 553, 555};
static __device__ const int    LV_AOFF[5]   = {0, 79872, 99840, 104832, 106080};
// Base anchors computed with np.round (half-even) semantics, verified by hand.
static __device__ const double BASE_ANCH[5][3][4] = {
  {{-22.,-10.,25.,13.},   {-14.,-14.,17.,17.},    {-10.,-22.,13.,25.}},
  {{-40.,-20.,47.,27.},   {-28.,-28.,35.,35.},    {-20.,-44.,27.,51.}},
  {{-84.,-40.,99.,55.},   {-56.,-56.,71.,71.},    {-36.,-80.,51.,95.}},
  {{-164.,-72.,195.,103.},{-112.,-112.,143.,143.},{-76.,-168.,107.,199.}},
  {{-332.,-152.,395.,215.},{-224.,-224.,287.,287.},{-148.,-328.,211.,391.}}
};

// ---------------- weight repack ----------------
// wp64[(ci*9+tap)*512 + c] = conv_w[c][ci][tap]  (f64)
// w1t[c*18 + j] = j<6 ? score_w[j][c] : bbox_w[j-6][c]  (f64)
__global__ __launch_bounds__(256) void k_repack(const float* __restrict__ cw,
                                                const float* __restrict__ sw,
                                                const float* __restrict__ bw,
                                                double* __restrict__ wp64,
                                                double* __restrict__ w1t) {
  int i = blockIdx.x * 256 + threadIdx.x;
  if (i < 1179648) {
    int c = i & 511, rt = i >> 9;
    wp64[i] = (double)cw[c * 2304 + rt];
  } else if (i < 1179648 + 9216) {
    int k = i - 1179648;
    int c = k / 18, j = k % 18;
    w1t[k] = (double)(j < 6 ? sw[j * 512 + c] : bw[(j - 6) * 512 + c]);
  }
}

// ---------------- fused conv3x3 + heads + decode ----------------
__global__ __launch_bounds__(256) void k_conv(
    const float* __restrict__ p0, const float* __restrict__ p1,
    const float* __restrict__ p2, const float* __restrict__ p3,
    const float* __restrict__ p4,
    const float* __restrict__ cb, const float* __restrict__ sbias,
    const float* __restrict__ bbias, const float* __restrict__ im_info,
    const double* __restrict__ wp64, const double* __restrict__ w1t,
    double* __restrict__ scores, double* __restrict__ boxes) {
  __shared__ double red[4][64][18];
  int tid = threadIdx.x, wv = tid >> 6, ln = tid & 63;
  int t = blockIdx.x;
  int L = 0;
  while (L < 4 && t >= LV_TILE0[L + 1]) ++L;
  const float* inL = (L == 0) ? p0 : (L == 1) ? p1 : (L == 2) ? p2 : (L == 3) ? p3 : p4;
  int H = LV_H[L], W = LV_W[L], HW = H * W, PIX = LV_PIX[L];
  int pix = (t - LV_TILE0[L]) * 64 + ln;
  if (pix >= PIX) pix = PIX - 1;   // duplicate tail lanes (benign same-value writes)
  int h = pix / W, w = pix % W;
  bool rok[3], cok[3];
  int roff[3];
#pragma unroll
  for (int ky = 0; ky < 3; ++ky) {
    int iy = h + ky - 1;
    rok[ky] = (iy >= 0 && iy < H);
    roff[ky] = iy * W + w - 1;
  }
#pragma unroll
  for (int kx = 0; kx < 3; ++kx) {
    int ix = w + kx - 1;
    cok[kx] = (ix >= 0 && ix < W);
  }
  double part[18];
#pragma unroll
  for (int j = 0; j < 18; ++j) part[j] = 0.0;

#pragma unroll 1
  for (int oc = 0; oc < 16; ++oc) {
    int c0 = oc * 32 + wv * 8;
    double acc[8];
#pragma unroll
    for (int q = 0; q < 8; ++q) acc[q] = (double)cb[c0 + q];
#pragma unroll 1
    for (int ci = 0; ci < 256; ++ci) {
      const float* ib = inL + ci * HW;
      const double* wr = wp64 + ((ci * 9) << 9) + c0;
#pragma unroll
      for (int ky = 0; ky < 3; ++ky) {
#pragma unroll
        for (int kx = 0; kx < 3; ++kx) {
          float v = (rok[ky] && cok[kx]) ? ib[roff[ky] + kx] : 0.0f;
          double vd = (double)v;
          const double4* w4 = (const double4*)(wr + (((ky * 3) + kx) << 9));
          double4 wA = w4[0], wB = w4[1];
          acc[0] += vd * wA.x; acc[1] += vd * wA.y;
          acc[2] += vd * wA.z; acc[3] += vd * wA.w;
          acc[4] += vd * wB.x; acc[5] += vd * wB.y;
          acc[6] += vd * wB.z; acc[7] += vd * wB.w;
        }
      }
    }
#pragma unroll
    for (int q = 0; q < 8; ++q) {
      const double* w1 = w1t + (c0 + q) * 18;
      double f = acc[q];
#pragma unroll
      for (int j = 0; j < 18; ++j) part[j] += f * w1[j];
    }
  }
#pragma unroll
  for (int j = 0; j < 18; ++j) red[wv][ln][j] = part[j];
  __syncthreads();
  if (wv == 0) {
    double fin[18];
#pragma unroll
    for (int j = 0; j < 18; ++j)
      fin[j] = red[0][ln][j] + red[1][ln][j] + red[2][ln][j] + red[3][ln][j];
    double imW1 = (double)im_info[1] - 1.0;
    double imH1 = (double)im_info[0] - 1.0;
    int stride = LV_STRIDE[L];
    double shx = (double)(w * stride), shy = (double)(h * stride);
    int gbase = LV_AOFF[L] + pix * 3;
#pragma unroll
    for (int a = 0; a < 3; ++a) {
      double lgt = (fin[3 + a] + (double)sbias[3 + a]) - (fin[a] + (double)sbias[a]);
      double s = 1.0 / (1.0 + exp(-lgt));      // == softmax fg prob
      double dx = fin[6 + 4 * a + 0] + (double)bbias[4 * a + 0];
      double dy = fin[6 + 4 * a + 1] + (double)bbias[4 * a + 1];
      double dw = fin[6 + 4 * a + 2] + (double)bbias[4 * a + 2];
      double dh = fin[6 + 4 * a + 3] + (double)bbias[4 * a + 3];
      double ax1 = BASE_ANCH[L][a][0] + shx, ay1 = BASE_ANCH[L][a][1] + shy;
      double ax2 = BASE_ANCH[L][a][2] + shx, ay2 = BASE_ANCH[L][a][3] + shy;
      double wa = ax2 - ax1 + 1.0, ha = ay2 - ay1 + 1.0;
      double cx = ax1 + 0.5 * wa, cy = ay1 + 0.5 * ha;
      double pcx = dx * wa + cx, pcy = dy * ha + cy;
      double pw = exp(dw) * wa, ph = exp(dh) * ha;
      double x1 = pcx - 0.5 * pw, y1 = pcy - 0.5 * ph;
      double x2 = pcx + 0.5 * pw, y2 = pcy + 0.5 * ph;
      x1 = fmin(fmax(x1, 0.0), imW1);
      y1 = fmin(fmax(y1, 0.0), imH1);
      x2 = fmin(fmax(x2, 0.0), imW1);
      y2 = fmin(fmax(y2, 0.0), imH1);
      int g = gbase + a;
      scores[g] = s;
      boxes[g * 4 + 0] = x1; boxes[g * 4 + 1] = y1;
      boxes[g * 4 + 2] = x2; boxes[g * 4 + 3] = y2;
    }
  }
}

// ---------------- top-k: histogram / edge / compact / sort ----------------
__global__ __launch_bounds__(256) void k_hist(const double* __restrict__ scores,
                                              uint32_t* __restrict__ hist) {
  int i = blockIdx.x * 256 + threadIdx.x;
  if (i < N_ANCH) {
    float sf = (float)scores[i];           // monotone under f64 order
    atomicAdd(&hist[__float_as_uint(sf) >> 16], 1u);
  }
}

__global__ __launch_bounds__(1024) void k_edge(const uint32_t* __restrict__ hist,
                                               uint32_t* __restrict__ cnts) {
  __shared__ uint32_t cs[1024];
  int t = threadIdx.x;
  uint32_t s = 0;
  for (int b = t * 64; b < t * 64 + 64; ++b) s += hist[b];
  cs[t] = s;
  __syncthreads();
  for (int off = 1; off < 1024; off <<= 1) {
    uint32_t v = cs[t] + ((t + off < 1024) ? cs[t + off] : 0u);
    __syncthreads();
    cs[t] = v;
    __syncthreads();
  }
  uint32_t sufnext = (t < 1023) ? cs[t + 1] : 0u;
  if (cs[t] >= PRE_NMS && sufnext < PRE_NMS) {   // unique t
    uint32_t run = sufnext;
    int edge = t * 64;
    for (int b = t * 64 + 63; b >= t * 64; --b) {
      run += hist[b];
      if (run >= PRE_NMS) { edge = b; break; }
    }
    cnts[1] = (uint32_t)edge;
  }
}

__global__ __launch_bounds__(256) void k_compact(const double* __restrict__ scores,
                                                 uint32_t* __restrict__ cnts,
                                                 uint64_t* __restrict__ pkey,
                                                 uint32_t* __restrict__ pidx) {
  int i = blockIdx.x * 256 + threadIdx.x;
  if (i >= N_ANCH) return;
  double s = scores[i];
  uint32_t bin = __float_as_uint((float)s) >> 16;
  if (bin >= cnts[1]) {
    uint32_t pos = atomicAdd(&cnts[0], 1u);
    if (pos < POOL_CAP) {
      uint64_t sb = (uint64_t)__double_as_longlong(s);  // s>0: bits are monotone
      pkey[pos] = ((sb >> 16) << 16) | (uint64_t)pos;   // 48-bit score + pool pos
      pidx[pos] = (uint32_t)i;
    }
  }
}

__global__ __launch_bounds__(1024) void k_sort(const uint32_t* __restrict__ cnts,
                                               const uint64_t* __restrict__ pkey,
                                               const uint32_t* __restrict__ pidx,
                                               const double* __restrict__ scores,
                                               const double* __restrict__ boxes,
                                               double* __restrict__ ss,
                                               double* __restrict__ sbx) {
  __shared__ uint64_t key[SORT_N];   // 64 KB
  int t = threadIdx.x;
  int cnt = (int)cnts[0];
  if (cnt > POOL_CAP) cnt = POOL_CAP;
  for (int e = t; e < SORT_N; e += 1024) key[e] = (e < cnt) ? pkey[e] : 0ull;
  __syncthreads();
  for (int k = 2; k <= SORT_N; k <<= 1) {
    for (int j = k >> 1; j > 0; j >>= 1) {
      for (int e = t; e < SORT_N; e += 1024) {
        int x = e ^ j;
        if (x > e) {
          uint64_t a = key[e], b = key[x];
          bool inv = (e & k) != 0;
          if (inv ? (a > b) : (a < b)) { key[e] = b; key[x] = a; }  // descending
        }
      }
      __syncthreads();
    }
  }
  for (int r = t; r < NMS_BLKS * 64; r += 1024) {
    if (r < PRE_NMS) {
      int p = (int)(key[r] & 0xFFFFull);
      int gi = (int)pidx[p];
      ss[r] = scores[gi];
#pragma unroll
      for (int c = 0; c < 4; ++c) sbx[r * 4 + c] = boxes[gi * 4 + c];
    } else {
      ss[r] = -1.0;
#pragma unroll
      for (int c = 0; c < 4; ++c) sbx[r * 4 + c] = 0.0;
    }
  }
}

// ---------------- NMS ----------------
__device__ __forceinline__ bool iou_gt(const double* A, const double* B) {
  double areaA = (A[2] - A[0] + 1.0) * (A[3] - A[1] + 1.0);
  double areaB = (B[2] - B[0] + 1.0) * (B[3] - B[1] + 1.0);
  double xx1 = fmax(A[0], B[0]), yy1 = fmax(A[1], B[1]);
  double xx2 = fmin(A[2], B[2]), yy2 = fmin(A[3], B[3]);
  double iw = fmax(0.0, xx2 - xx1 + 1.0), ih = fmax(0.0, yy2 - yy1 + 1.0);
  double inter = iw * ih;
  return inter > 0.7 * (areaA + areaB - inter);   // union>0 always (w,h>=1)
}

__global__ __launch_bounds__(1024) void k_nms(const double* __restrict__ ss,
                                              const double* __restrict__ sbx,
                                              float* __restrict__ out) {
  __shared__ double kb[POST_NMS][4];
  __shared__ double ksc[POST_NMS];
  __shared__ double cur[64][4];
  __shared__ double csc[64];
  __shared__ unsigned int ext[64];
  __shared__ unsigned long long lrow[64];
  __shared__ unsigned long long keepmask;
  __shared__ int kcnt;
  int t = threadIdx.x;
  if (t == 0) kcnt = 0;
  __syncthreads();
  for (int b = 0; b < NMS_BLKS; ++b) {
    int i = b * 64 + t;
    if (t < 64) {
#pragma unroll
      for (int c = 0; c < 4; ++c) cur[t][c] = sbx[i * 4 + c];
      csc[t] = ss[i];
      ext[t] = (i >= PRE_NMS) ? 1u : 0u;
      lrow[t] = 0ull;
    }
    __syncthreads();
    int K = kcnt;
    for (int p = t; p < K * 64; p += 1024) {
      int k = p >> 6, ii = p & 63;
      if (!ext[ii]) {
        if (iou_gt(kb[k], cur[ii])) ext[ii] = 1u;   // benign same-value race
      }
    }
    {   // local 64x64 suppression matrix, 4 cols per thread
      int i0 = t & 63, q = t >> 6;
      unsigned long long bits = 0ull;
#pragma unroll
      for (int jj = 0; jj < 4; ++jj) {
        int j = q * 4 + jj;
        if (j > i0 && iou_gt(cur[i0], cur[j])) bits |= 1ull << j;
      }
      if (bits) atomicOr(&lrow[i0], bits);
    }
    __syncthreads();
    if (t < 64) {   // wave 0: serial bitmask scan
      unsigned long long myrow = lrow[t];
      unsigned long long extm = __ballot(ext[t] != 0u);
      unsigned long long rm = 0ull, kp = 0ull;
      for (int i2 = 0; i2 < 64; ++i2) {
        unsigned long long row = __shfl(myrow, i2);
        if (!(((rm >> i2) & 1ull) | ((extm >> i2) & 1ull))) {
          rm |= row;
          kp |= 1ull << i2;
        }
      }
      if (t == 0) keepmask = kp;
    }
    __syncthreads();
    unsigned long long kp = keepmask;
    int K0 = kcnt;
    int avail = POST_NMS - K0;
    if (t < 64 && ((kp >> t) & 1ull)) {
      int r = __popcll(kp & ((1ull << t) - 1ull));
      if (r < avail) {
        int slot = K0 + r;
#pragma unroll
        for (int c = 0; c < 4; ++c) kb[slot][c] = cur[t][c];
        ksc[slot] = csc[t];
      }
    }
    __syncthreads();
    if (t == 0) {
      int nk = __popcll(kp);
      kcnt = (K0 + nk > POST_NMS) ? POST_NMS : K0 + nk;
    }
    __syncthreads();
    if (kcnt >= POST_NMS) break;
  }
  int KF = kcnt;
  for (int r = t; r < POST_NMS; r += 1024) {
    float* o = out + r * 6;
    if (r < KF) {
      o[0] = 0.f;
      o[1] = (float)kb[r][0];
      o[2] = (float)kb[r][1];
      o[3] = (float)kb[r][2];
      o[4] = (float)kb[r][3];
      o[5] = (float)ksc[r];
    } else {
#pragma unroll
      for (int c = 0; c < 6; ++c) o[c] = 0.f;
    }
  }
}

// ---------------- host launch ----------------
extern "C" void kernel_launch(void* const* d_in, const int* in_sizes, int n_in,
                              void* d_out, int out_size, void* d_ws, size_t ws_size,
                              hipStream_t stream) {
  const float* p0 = (const float*)d_in[0];
  const float* p1 = (const float*)d_in[1];
  const float* p2 = (const float*)d_in[2];
  const float* p3 = (const float*)d_in[3];
  const float* p4 = (const float*)d_in[4];
  const float* im_info = (const float*)d_in[5];
  const float* cw = (const float*)d_in[6];
  const float* cb = (const float*)d_in[7];
  const float* sw = (const float*)d_in[8];
  const float* sb = (const float*)d_in[9];
  const float* bw = (const float*)d_in[10];
  const float* bb = (const float*)d_in[11];
  char* ws = (char*)d_ws;
  // ws layout (bytes):
  uint32_t* hist = (uint32_t*)(ws + 0);          //  65536 u32 = 256 KB
  uint32_t* cnts = (uint32_t*)(ws + 262144);     //  [0]=pool_count [1]=edge
  double* scores = (double*)(ws + 262208);       //  106392 f64
  double* boxes  = (double*)(ws + 1113344);      //  106392*4 f64
  double* wp64   = (double*)(ws + 4517888);      //  1179648 f64
  double* w1t    = (double*)(ws + 13955072);     //  9216 f64
  uint64_t* pkey = (uint64_t*)(ws + 14028800);   //  8192 u64
  uint32_t* pidx = (uint32_t*)(ws + 14094336);   //  8192 u32
  double* ssort  = (double*)(ws + 14127104);     //  6016 f64
  double* sbx    = (double*)(ws + 14175232);     //  6016*4 f64  (end 14367744)
  float* out = (float*)d_out;

  hipMemsetAsync(ws, 0, 262208, stream);                 // hist + counters
  k_repack<<<4644, 256, 0, stream>>>(cw, sw, bw, wp64, w1t);
  k_conv<<<555, 256, 0, stream>>>(p0, p1, p2, p3, p4, cb, sb, bb, im_info,
                                  wp64, w1t, scores, boxes);
  k_hist<<<416, 256, 0, stream>>>(scores, hist);
  k_edge<<<1, 1024, 0, stream>>>(hist, cnts);
  k_compact<<<416, 256, 0, stream>>>(scores, cnts, pkey, pidx);
  k_sort<<<1, 1024, 0, stream>>>(cnts, pkey, pidx, scores, boxes, ssort, sbx);
  k_nms<<<1, 1024, 0, stream>>>(ssort, sbx, out);
}

// Round 2
// 1148.848 us; speedup vs baseline: 19.3506x; 19.3506x over previous
//
#include <hip/hip_runtime.h>
#include <stdint.h>

#define N_ANCH   106392
#define PRE_NMS  6000
#define POST_NMS 1000
#define POOL_CAP 8192
#define SORT_N   8192
#define NMS_BLKS 94   // 94*64 = 6016 >= 6000

static __device__ const int    LV_H[5]      = {128, 64, 32, 16, 8};
static __device__ const int    LV_W[5]      = {208, 104, 52, 26, 13};
static __device__ const int    LV_STRIDE[5] = {4, 8, 16, 32, 64};
static __device__ const int    LV_PIX[5]    = {26624, 6656, 1664, 416, 104};
static __device__ const int    LV_TILE0[6]  = {0, 416, 520, 546, 553, 555};
static __device__ const int    LV_AOFF[6]   = {0, 79872, 99840, 104832, 106080, 106392};
// Base anchors computed with np.round (half-even) semantics, verified by hand.
static __device__ const double BASE_ANCH[5][3][4] = {
  {{-22.,-10.,25.,13.},   {-14.,-14.,17.,17.},    {-10.,-22.,13.,25.}},
  {{-40.,-20.,47.,27.},   {-28.,-28.,35.,35.},    {-20.,-44.,27.,51.}},
  {{-84.,-40.,99.,55.},   {-56.,-56.,71.,71.},    {-36.,-80.,51.,95.}},
  {{-164.,-72.,195.,103.},{-112.,-112.,143.,143.},{-76.,-168.,107.,199.}},
  {{-332.,-152.,395.,215.},{-224.,-224.,287.,287.},{-148.,-328.,211.,391.}}
};

// ---------------- head-weight combine ----------------
// comb[c][j] : j<3 -> sw[3+j][c]-sw[j][c]   (fg-bg logit diff weights)
//              3<=j<15 -> bw[j-3][c]        (bbox delta weights)
//              j=15 -> 0 (pad)
__global__ __launch_bounds__(256) void k_comb(const float* __restrict__ sw,
                                              const float* __restrict__ bw,
                                              double* __restrict__ comb) {
  int c = blockIdx.x * 256 + threadIdx.x;
  if (c >= 512) return;
#pragma unroll
  for (int j = 0; j < 16; ++j) {
    double v = 0.0;
    if (j < 3)       v = (double)sw[(3 + j) * 512 + c] - (double)sw[j * 512 + c];
    else if (j < 15) v = (double)bw[(j - 3) * 512 + c];
    comb[c * 16 + j] = v;
  }
}

// ---------------- effective weight fold ----------------
// Weff[t][j] = sum_c cw[c*2304 + t] * comb[c][j]   (t = ci*9 + ky*3 + kx)
// fb[j]      = sum_c cb[c] * comb[c][j] + head_bias_j
__global__ __launch_bounds__(256) void k_weff(const float* __restrict__ cw,
                                              const float* __restrict__ cb,
                                              const float* __restrict__ sb,
                                              const float* __restrict__ bb,
                                              const double* __restrict__ comb,
                                              double* __restrict__ Weff,
                                              double* __restrict__ fb) {
  if (blockIdx.x == 9) {   // bias fold
    int j = threadIdx.x;
    if (j < 15) {
      double s = 0.0;
      for (int c = 0; c < 512; ++c) s += (double)cb[c] * comb[c * 16 + j];
      s += (j < 3) ? ((double)sb[3 + j] - (double)sb[j]) : (double)bb[j - 3];
      fb[j] = s;
    }
    return;
  }
  int t = blockIdx.x * 256 + threadIdx.x;
  if (t >= 2304) return;
  double acc[15];
#pragma unroll
  for (int j = 0; j < 15; ++j) acc[j] = 0.0;
#pragma unroll 1
  for (int c = 0; c < 512; ++c) {
    double v = (double)cw[c * 2304 + t];
    const double* cm = comb + c * 16;
#pragma unroll
    for (int j = 0; j < 15; ++j) acc[j] += v * cm[j];
  }
  double* o = Weff + (t << 4);
#pragma unroll
  for (int j = 0; j < 15; ++j) o[j] = acc[j];
  o[15] = 0.0;
}

// ---------------- fused folded conv: 15 outputs/pixel ----------------
__global__ __launch_bounds__(256) void k_conv15(
    const float* __restrict__ p0, const float* __restrict__ p1,
    const float* __restrict__ p2, const float* __restrict__ p3,
    const float* __restrict__ p4,
    const double* __restrict__ Weff, const double* __restrict__ fb,
    double* __restrict__ logits, double* __restrict__ deltas) {
  __shared__ double red[4][64][15];
  int tid = threadIdx.x, wv = tid >> 6, ln = tid & 63;
  int t = blockIdx.x;
  int L = 0;
  while (L < 4 && t >= LV_TILE0[L + 1]) ++L;
  const float* inL = (L == 0) ? p0 : (L == 1) ? p1 : (L == 2) ? p2 : (L == 3) ? p3 : p4;
  int H = LV_H[L], W = LV_W[L], HW = H * W, PIX = LV_PIX[L];
  int pix = (t - LV_TILE0[L]) * 64 + ln;
  if (pix >= PIX) pix = PIX - 1;   // duplicate tail lanes (identical-value writes)
  int h = pix / W, w = pix % W;
  bool rok[3], cok[3];
  int roff[3];
#pragma unroll
  for (int ky = 0; ky < 3; ++ky) {
    int iy = h + ky - 1;
    rok[ky] = (iy >= 0 && iy < H);
    roff[ky] = iy * W + w - 1;
  }
#pragma unroll
  for (int kx = 0; kx < 3; ++kx) {
    int ix = w + kx - 1;
    cok[kx] = (ix >= 0 && ix < W);
  }
  double acc[15];
#pragma unroll
  for (int j = 0; j < 15; ++j) acc[j] = 0.0;
  int ci0 = wv * 64;
#pragma unroll 1
  for (int ci = ci0; ci < ci0 + 64; ++ci) {
    const float* ib = inL + ci * HW;
    float v[9];
#pragma unroll
    for (int ky = 0; ky < 3; ++ky)
#pragma unroll
      for (int kx = 0; kx < 3; ++kx)
        v[ky * 3 + kx] = (rok[ky] && cok[kx]) ? ib[roff[ky] + kx] : 0.0f;
    const double* wr = Weff + ((ci * 9) << 4);
#pragma unroll
    for (int t9 = 0; t9 < 9; ++t9) {
      double vd = (double)v[t9];
      const double* wt = wr + (t9 << 4);   // wave-uniform -> scalar loads
#pragma unroll
      for (int j = 0; j < 15; ++j) acc[j] += vd * wt[j];
    }
  }
#pragma unroll
  for (int j = 0; j < 15; ++j) red[wv][ln][j] = acc[j];
  __syncthreads();
  if (wv == 0) {
    double fin[15];
#pragma unroll
    for (int j = 0; j < 15; ++j)
      fin[j] = (red[0][ln][j] + red[1][ln][j] + red[2][ln][j] + red[3][ln][j]) + fb[j];
    int gbase = LV_AOFF[L] + pix * 3;
#pragma unroll
    for (int a = 0; a < 3; ++a) {
      int g = gbase + a;
      logits[g] = fin[a];
      deltas[g * 4 + 0] = fin[3 + 4 * a + 0];
      deltas[g * 4 + 1] = fin[3 + 4 * a + 1];
      deltas[g * 4 + 2] = fin[3 + 4 * a + 2];
      deltas[g * 4 + 3] = fin[3 + 4 * a + 3];
    }
  }
}

// sortable mappings (monotone): bigger logit -> bigger key
__device__ __forceinline__ uint32_t sort32(double d) {
  uint32_t u = __float_as_uint((float)d);
  return ((int)u < 0) ? ~u : (u | 0x80000000u);
}
__device__ __forceinline__ uint64_t sort64(double d) {
  uint64_t u = (uint64_t)__double_as_longlong(d);
  return ((long long)u < 0) ? ~u : (u | 0x8000000000000000ull);
}

// ---------------- top-k: histogram / edge / compact / sort ----------------
__global__ __launch_bounds__(256) void k_hist(const double* __restrict__ logits,
                                              uint32_t* __restrict__ hist) {
  int i = blockIdx.x * 256 + threadIdx.x;
  if (i < N_ANCH) atomicAdd(&hist[sort32(logits[i]) >> 16], 1u);
}

__global__ __launch_bounds__(1024) void k_edge(const uint32_t* __restrict__ hist,
                                               uint32_t* __restrict__ cnts) {
  __shared__ uint32_t cs[1024];
  int t = threadIdx.x;
  uint32_t s = 0;
  for (int b = t * 64; b < t * 64 + 64; ++b) s += hist[b];
  cs[t] = s;
  __syncthreads();
  for (int off = 1; off < 1024; off <<= 1) {
    uint32_t v = cs[t] + ((t + off < 1024) ? cs[t + off] : 0u);
    __syncthreads();
    cs[t] = v;
    __syncthreads();
  }
  uint32_t sufnext = (t < 1023) ? cs[t + 1] : 0u;
  if (cs[t] >= PRE_NMS && sufnext < PRE_NMS) {   // unique t
    uint32_t run = sufnext;
    int edge = t * 64;
    for (int b = t * 64 + 63; b >= t * 64; --b) {
      run += hist[b];
      if (run >= PRE_NMS) { edge = b; break; }
    }
    cnts[1] = (uint32_t)edge;
  }
}

__global__ __launch_bounds__(256) void k_compact(const double* __restrict__ logits,
                                                 uint32_t* __restrict__ cnts,
                                                 uint64_t* __restrict__ pkey) {
  int i = blockIdx.x * 256 + threadIdx.x;
  if (i >= N_ANCH) return;
  double lg = logits[i];
  if ((sort32(lg) >> 16) >= cnts[1]) {
    uint32_t pos = atomicAdd(&cnts[0], 1u);
    if (pos < POOL_CAP) {
      // top-47 bits of sortable score; low 17 bits encode index (inverted ->
      // descending sort breaks score ties by ascending index, like top_k)
      pkey[pos] = (sort64(lg) & ~0x1FFFFull) | (uint64_t)(0x1FFFFu - (uint32_t)i);
    }
  }
}

__global__ __launch_bounds__(1024) void k_sort(const uint32_t* __restrict__ cnts,
                                               const uint64_t* __restrict__ pkey,
                                               const double* __restrict__ logits,
                                               const double* __restrict__ deltas,
                                               const float* __restrict__ im_info,
                                               double* __restrict__ ss,
                                               double* __restrict__ sbx) {
  __shared__ uint64_t key[SORT_N];   // 64 KB
  int t = threadIdx.x;
  int cnt = (int)cnts[0];
  if (cnt > POOL_CAP) cnt = POOL_CAP;
  for (int e = t; e < SORT_N; e += 1024) key[e] = (e < cnt) ? pkey[e] : 0ull;
  __syncthreads();
  for (int k = 2; k <= SORT_N; k <<= 1) {
    for (int j = k >> 1; j > 0; j >>= 1) {
      for (int e = t; e < SORT_N; e += 1024) {
        int x = e ^ j;
        if (x > e) {
          uint64_t a = key[e], b = key[x];
          bool inv = (e & k) != 0;
          if (inv ? (a > b) : (a < b)) { key[e] = b; key[x] = a; }  // descending
        }
      }
      __syncthreads();
    }
  }
  double imW1 = (double)im_info[1] - 1.0;
  double imH1 = (double)im_info[0] - 1.0;
  for (int r = t; r < NMS_BLKS * 64; r += 1024) {
    if (r < PRE_NMS) {
      int gi = 0x1FFFF - (int)(key[r] & 0x1FFFFull);
      int L = 0;
      while (L < 4 && gi >= LV_AOFF[L + 1]) ++L;
      int rel = gi - LV_AOFF[L];
      int pix = rel / 3, a = rel % 3;
      int W = LV_W[L];
      int h = pix / W, w = pix % W;
      double shx = (double)(w * LV_STRIDE[L]), shy = (double)(h * LV_STRIDE[L]);
      double ax1 = BASE_ANCH[L][a][0] + shx, ay1 = BASE_ANCH[L][a][1] + shy;
      double ax2 = BASE_ANCH[L][a][2] + shx, ay2 = BASE_ANCH[L][a][3] + shy;
      double dx = deltas[gi * 4 + 0], dy = deltas[gi * 4 + 1];
      double dw = deltas[gi * 4 + 2], dh = deltas[gi * 4 + 3];
      double wa = ax2 - ax1 + 1.0, ha = ay2 - ay1 + 1.0;
      double cx = ax1 + 0.5 * wa, cy = ay1 + 0.5 * ha;
      double pcx = dx * wa + cx, pcy = dy * ha + cy;
      double pw = exp(dw) * wa, ph = exp(dh) * ha;
      double x1 = fmin(fmax(pcx - 0.5 * pw, 0.0), imW1);
      double y1 = fmin(fmax(pcy - 0.5 * ph, 0.0), imH1);
      double x2 = fmin(fmax(pcx + 0.5 * pw, 0.0), imW1);
      double y2 = fmin(fmax(pcy + 0.5 * ph, 0.0), imH1);
      ss[r] = 1.0 / (1.0 + exp(-logits[gi]));
      sbx[r * 4 + 0] = x1; sbx[r * 4 + 1] = y1;
      sbx[r * 4 + 2] = x2; sbx[r * 4 + 3] = y2;
    } else {
      ss[r] = -1.0;
#pragma unroll
      for (int c = 0; c < 4; ++c) sbx[r * 4 + c] = 0.0;
    }
  }
}

// ---------------- NMS ----------------
__device__ __forceinline__ bool iou_gt(const double* A, const double* B) {
  double areaA = (A[2] - A[0] + 1.0) * (A[3] - A[1] + 1.0);
  double areaB = (B[2] - B[0] + 1.0) * (B[3] - B[1] + 1.0);
  double xx1 = fmax(A[0], B[0]), yy1 = fmax(A[1], B[1]);
  double xx2 = fmin(A[2], B[2]), yy2 = fmin(A[3], B[3]);
  double iw = fmax(0.0, xx2 - xx1 + 1.0), ih = fmax(0.0, yy2 - yy1 + 1.0);
  double inter = iw * ih;
  return inter > 0.7 * (areaA + areaB - inter);   // union>0 always (w,h>=1)
}

__global__ __launch_bounds__(1024) void k_nms(const double* __restrict__ ss,
                                              const double* __restrict__ sbx,
                                              float* __restrict__ out) {
  __shared__ double kb[POST_NMS][4];
  __shared__ double ksc[POST_NMS];
  __shared__ double cur[64][4];
  __shared__ double csc[64];
  __shared__ unsigned int ext[64];
  __shared__ unsigned long long lrow[64];
  __shared__ unsigned long long keepmask;
  __shared__ int kcnt;
  int t = threadIdx.x;
  if (t == 0) kcnt = 0;
  __syncthreads();
  for (int b = 0; b < NMS_BLKS; ++b) {
    int i = b * 64 + t;
    if (t < 64) {
#pragma unroll
      for (int c = 0; c < 4; ++c) cur[t][c] = sbx[i * 4 + c];
      csc[t] = ss[i];
      ext[t] = (i >= PRE_NMS) ? 1u : 0u;
      lrow[t] = 0ull;
    }
    __syncthreads();
    int K = kcnt;
    for (int p = t; p < K * 64; p += 1024) {
      int k = p >> 6, ii = p & 63;
      if (!ext[ii]) {
        if (iou_gt(kb[k], cur[ii])) ext[ii] = 1u;   // benign same-value race
      }
    }
    {   // local 64x64 suppression matrix, 4 cols per thread
      int i0 = t & 63, q = t >> 6;
      unsigned long long bits = 0ull;
#pragma unroll
      for (int jj = 0; jj < 4; ++jj) {
        int j = q * 4 + jj;
        if (j > i0 && iou_gt(cur[i0], cur[j])) bits |= 1ull << j;
      }
      if (bits) atomicOr(&lrow[i0], bits);
    }
    __syncthreads();
    if (t < 64) {   // wave 0: serial bitmask scan
      unsigned long long myrow = lrow[t];
      unsigned long long extm = __ballot(ext[t] != 0u);
      unsigned long long rm = 0ull, kp = 0ull;
      for (int i2 = 0; i2 < 64; ++i2) {
        unsigned long long row = __shfl(myrow, i2);
        if (!(((rm >> i2) & 1ull) | ((extm >> i2) & 1ull))) {
          rm |= row;
          kp |= 1ull << i2;
        }
      }
      if (t == 0) keepmask = kp;
    }
    __syncthreads();
    unsigned long long kp = keepmask;
    int K0 = kcnt;
    int avail = POST_NMS - K0;
    if (t < 64 && ((kp >> t) & 1ull)) {
      int r = __popcll(kp & ((1ull << t) - 1ull));
      if (r < avail) {
        int slot = K0 + r;
#pragma unroll
        for (int c = 0; c < 4; ++c) kb[slot][c] = cur[t][c];
        ksc[slot] = csc[t];
      }
    }
    __syncthreads();
    if (t == 0) {
      int nk = __popcll(kp);
      kcnt = (K0 + nk > POST_NMS) ? POST_NMS : K0 + nk;
    }
    __syncthreads();
    if (kcnt >= POST_NMS) break;
  }
  int KF = kcnt;
  for (int r = t; r < POST_NMS; r += 1024) {
    float* o = out + r * 6;
    if (r < KF) {
      o[0] = 0.f;
      o[1] = (float)kb[r][0];
      o[2] = (float)kb[r][1];
      o[3] = (float)kb[r][2];
      o[4] = (float)kb[r][3];
      o[5] = (float)ksc[r];
    } else {
#pragma unroll
      for (int c = 0; c < 6; ++c) o[c] = 0.f;
    }
  }
}

// ---------------- host launch ----------------
extern "C" void kernel_launch(void* const* d_in, const int* in_sizes, int n_in,
                              void* d_out, int out_size, void* d_ws, size_t ws_size,
                              hipStream_t stream) {
  const float* p0 = (const float*)d_in[0];
  const float* p1 = (const float*)d_in[1];
  const float* p2 = (const float*)d_in[2];
  const float* p3 = (const float*)d_in[3];
  const float* p4 = (const float*)d_in[4];
  const float* im_info = (const float*)d_in[5];
  const float* cw = (const float*)d_in[6];
  const float* cb = (const float*)d_in[7];
  const float* sw = (const float*)d_in[8];
  const float* sb = (const float*)d_in[9];
  const float* bw = (const float*)d_in[10];
  const float* bb = (const float*)d_in[11];
  char* ws = (char*)d_ws;
  // ws layout (bytes):
  uint32_t* hist  = (uint32_t*)(ws + 0);         // 65536 u32 = 262144 B
  uint32_t* cnts  = (uint32_t*)(ws + 262144);    // 256 B reserved
  double*  fb     = (double*)  (ws + 262400);    // 16 f64  -> 262528
  double*  logits = (double*)  (ws + 262528);    // 106392 f64 -> 1113664
  double*  deltas = (double*)  (ws + 1113664);   // 425568 f64 -> 4518208
  double*  comb   = (double*)  (ws + 4518208);   // 512*16 f64 -> 4583744
  double*  Weff   = (double*)  (ws + 4583744);   // 2304*16 f64 -> 4878656
  uint64_t* pkey  = (uint64_t*)(ws + 4878656);   // 8192 u64 -> 4944192
  double*  ssort  = (double*)  (ws + 4944192);   // 6016 f64 -> 4992320
  double*  sbx    = (double*)  (ws + 4992320);   // 6016*4 f64 -> 5184832
  float* out = (float*)d_out;

  hipMemsetAsync(ws, 0, 262656, stream);                 // hist + counters
  k_comb<<<2, 256, 0, stream>>>(sw, bw, comb);
  k_weff<<<10, 256, 0, stream>>>(cw, cb, sb, bb, comb, Weff, fb);
  k_conv15<<<555, 256, 0, stream>>>(p0, p1, p2, p3, p4, Weff, fb, logits, deltas);
  k_hist<<<416, 256, 0, stream>>>(logits, hist);
  k_edge<<<1, 1024, 0, stream>>>(hist, cnts);
  k_compact<<<416, 256, 0, stream>>>(logits, cnts, pkey);
  k_sort<<<1, 1024, 0, stream>>>(cnts, pkey, logits, deltas, im_info, ssort, sbx);
  k_nms<<<1, 1024, 0, stream>>>(ssort, sbx, out);
}

// Round 4
// 1096.446 us; speedup vs baseline: 20.2754x; 1.0478x over previous
//
#include <hip/hip_runtime.h>
#include <stdint.h>

#define N_ANCH   106392
#define PRE_NMS  6000
#define POST_NMS 1000
#define POOL_CAP 8192
#define SORT_N   8192
#define NMS_BLKS 94   // 94*64 = 6016 >= 6000

static __device__ const int    LV_H[5]      = {128, 64, 32, 16, 8};
static __device__ const int    LV_W[5]      = {208, 104, 52, 26, 13};
static __device__ const int    LV_STRIDE[5] = {4, 8, 16, 32, 64};
static __device__ const int    LV_PIX[5]    = {26624, 6656, 1664, 416, 104};
static __device__ const int    LV_TILE0[6]  = {0, 416, 520, 546, 553, 555};
static __device__ const int    LV_AOFF[6]   = {0, 79872, 99840, 104832, 106080, 106392};
// Base anchors computed with np.round (half-even) semantics, verified by hand.
static __device__ const double BASE_ANCH[5][3][4] = {
  {{-22.,-10.,25.,13.},   {-14.,-14.,17.,17.},    {-10.,-22.,13.,25.}},
  {{-40.,-20.,47.,27.},   {-28.,-28.,35.,35.},    {-20.,-44.,27.,51.}},
  {{-84.,-40.,99.,55.},   {-56.,-56.,71.,71.},    {-36.,-80.,51.,95.}},
  {{-164.,-72.,195.,103.},{-112.,-112.,143.,143.},{-76.,-168.,107.,199.}},
  {{-332.,-152.,395.,215.},{-224.,-224.,287.,287.},{-148.,-328.,211.,391.}}
};

// Opaque zero: compiler cannot constant-fold ds_bpermute, so pointer+z is
// treated as divergent -> weight loads go down the VMEM path (in-order vmcnt,
// pipelinable) instead of out-of-order SMEM s_loads (lgkmcnt(0) serialization).
__device__ __forceinline__ int opaque_zero() {
  return __builtin_amdgcn_ds_bpermute(0, 0);
}

// ---------------- head-weight combine ----------------
// comb[c][j] : j<3 -> sw[3+j][c]-sw[j][c]; 3<=j<15 -> bw[j-3][c]; j=15 pad
__global__ __launch_bounds__(256) void k_comb(const float* __restrict__ sw,
                                              const float* __restrict__ bw,
                                              double* __restrict__ comb) {
  int c = blockIdx.x * 256 + threadIdx.x;
  if (c >= 512) return;
#pragma unroll
  for (int j = 0; j < 16; ++j) {
    double v = 0.0;
    if (j < 3)       v = (double)sw[(3 + j) * 512 + c] - (double)sw[j * 512 + c];
    else if (j < 15) v = (double)bw[(j - 3) * 512 + c];
    comb[c * 16 + j] = v;
  }
}

// ---------------- effective weight fold, 2-stage parallel ----------------
// Wpart[chunk][t][j] = sum_{c in chunk*32..+32} cw[c*2304+t] * comb[c][j]
// grid = 16 chunks x 9 t-blocks of 256 -> taps covered exactly (9*256 = 2304)
__global__ __launch_bounds__(256) void k_weff_part(const float* __restrict__ cw,
                                                   const double* __restrict__ comb,
                                                   double* __restrict__ Wpart) {
  int chunk = blockIdx.x / 9;            // 16 chunks
  int tb = blockIdx.x % 9;               // 9 t-blocks of 256
  int t = tb * 256 + threadIdx.x;        // 0..2303, no gaps
  const double* combV = comb + opaque_zero();
  int c0 = chunk * 32;
  double acc[15];
#pragma unroll
  for (int j = 0; j < 15; ++j) acc[j] = 0.0;
#pragma unroll 2
  for (int c = c0; c < c0 + 32; ++c) {
    double v = (double)cw[c * 2304 + t];
    const double* cm = combV + (c << 4);
#pragma unroll
    for (int j = 0; j < 15; ++j) acc[j] += v * cm[j];
  }
  double* o = Wpart + (((size_t)chunk * 2304 + t) << 4);
#pragma unroll
  for (int j = 0; j < 15; ++j) o[j] = acc[j];
  o[15] = 0.0;
}

// Weff[t][j] = sum over chunks (ascending, deterministic order)
__global__ __launch_bounds__(256) void k_weff_red(const double* __restrict__ Wpart,
                                                  double* __restrict__ Weff) {
  int t = blockIdx.x * 256 + threadIdx.x;
  if (t >= 2304) return;
  double acc[15];
#pragma unroll
  for (int j = 0; j < 15; ++j) acc[j] = 0.0;
#pragma unroll 1
  for (int chunk = 0; chunk < 16; ++chunk) {
    const double* p = Wpart + (((size_t)chunk * 2304 + t) << 4);
#pragma unroll
    for (int j = 0; j < 15; ++j) acc[j] += p[j];
  }
  double* o = Weff + ((size_t)t << 4);
#pragma unroll
  for (int j = 0; j < 15; ++j) o[j] = acc[j];
  o[15] = 0.0;
}

// fb[j] = sum_c cb[c]*comb[c][j] + head_bias_j   (parallel over 15*16 threads)
__global__ __launch_bounds__(256) void k_bias(const float* __restrict__ cb,
                                              const float* __restrict__ sb,
                                              const float* __restrict__ bb,
                                              const double* __restrict__ comb,
                                              double* __restrict__ fb) {
  __shared__ double ps[15][16];
  int tid = threadIdx.x;
  const double* combV = comb + opaque_zero();
  if (tid < 240) {
    int j = tid >> 4, part = tid & 15;
    double s = 0.0;
    for (int c = part * 32; c < part * 32 + 32; ++c)
      s += (double)cb[c] * combV[(c << 4) + j];
    ps[j][part] = s;
  }
  __syncthreads();
  if (tid < 15) {
    double s = 0.0;
#pragma unroll
    for (int part = 0; part < 16; ++part) s += ps[tid][part];  // fixed order
    s += (tid < 3) ? ((double)sb[3 + tid] - (double)sb[tid]) : (double)bb[tid - 3];
    fb[tid] = s;
  }
}

// ---------------- fused folded conv: 15 outputs/pixel ----------------
__device__ __forceinline__ void load9(float v[9], const float* __restrict__ ib,
                                      const bool rok[3], const bool cok[3],
                                      const int roff[3]) {
#pragma unroll
  for (int ky = 0; ky < 3; ++ky)
#pragma unroll
    for (int kx = 0; kx < 3; ++kx)
      v[ky * 3 + kx] = (rok[ky] && cok[kx]) ? ib[roff[ky] + kx] : 0.0f;
}

__global__ __launch_bounds__(256) void k_conv15(
    const float* __restrict__ p0, const float* __restrict__ p1,
    const float* __restrict__ p2, const float* __restrict__ p3,
    const float* __restrict__ p4,
    const double* __restrict__ Weff, const double* __restrict__ fb,
    double* __restrict__ logits, double* __restrict__ deltas) {
  __shared__ double red[4][64][15];
  int tid = threadIdx.x, wv = tid >> 6, ln = tid & 63;
  int t = blockIdx.x;
  int L = 0;
  while (L < 4 && t >= LV_TILE0[L + 1]) ++L;
  const float* inL = (L == 0) ? p0 : (L == 1) ? p1 : (L == 2) ? p2 : (L == 3) ? p3 : p4;
  int H = LV_H[L], W = LV_W[L], HW = H * W, PIX = LV_PIX[L];
  int pix = (t - LV_TILE0[L]) * 64 + ln;
  if (pix >= PIX) pix = PIX - 1;   // duplicate tail lanes (identical-value writes)
  int h = pix / W, w = pix % W;
  bool rok[3], cok[3];
  int roff[3];
#pragma unroll
  for (int ky = 0; ky < 3; ++ky) {
    int iy = h + ky - 1;
    rok[ky] = (iy >= 0 && iy < H);
    roff[ky] = iy * W + w - 1;
  }
#pragma unroll
  for (int kx = 0; kx < 3; ++kx) {
    int ix = w + kx - 1;
    cok[kx] = (ix >= 0 && ix < W);
  }
  const double* WeffV = Weff + opaque_zero();  // force VMEM weight path
  double acc[15];
#pragma unroll
  for (int j = 0; j < 15; ++j) acc[j] = 0.0;
  int ci0 = wv * 64, ciE = ci0 + 64;
  float vn[9];
  load9(vn, inL + ci0 * HW, rok, cok, roff);   // prologue prefetch
#pragma unroll 2
  for (int ci = ci0; ci < ciE; ++ci) {
    float v[9];
#pragma unroll
    for (int q = 0; q < 9; ++q) v[q] = vn[q];
    int cin = (ci + 1 < ciE) ? ci + 1 : ci;    // next-channel prefetch
    load9(vn, inL + cin * HW, rok, cok, roff);
    const double* wr = WeffV + ((size_t)(ci * 9) << 4);
#pragma unroll
    for (int t9 = 0; t9 < 9; ++t9) {
      double vd = (double)v[t9];
      const double* wt = wr + (t9 << 4);
#pragma unroll
      for (int j = 0; j < 15; ++j) acc[j] += vd * wt[j];
    }
  }
#pragma unroll
  for (int j = 0; j < 15; ++j) red[wv][ln][j] = acc[j];
  __syncthreads();
  if (wv == 0) {
    double fin[15];
#pragma unroll
    for (int j = 0; j < 15; ++j)
      fin[j] = (red[0][ln][j] + red[1][ln][j] + red[2][ln][j] + red[3][ln][j]) + fb[j];
    int gbase = LV_AOFF[L] + pix * 3;
#pragma unroll
    for (int a = 0; a < 3; ++a) {
      int g = gbase + a;
      logits[g] = fin[a];
      deltas[g * 4 + 0] = fin[3 + 4 * a + 0];
      deltas[g * 4 + 1] = fin[3 + 4 * a + 1];
      deltas[g * 4 + 2] = fin[3 + 4 * a + 2];
      deltas[g * 4 + 3] = fin[3 + 4 * a + 3];
    }
  }
}

// sortable mappings (monotone): bigger logit -> bigger key
__device__ __forceinline__ uint32_t sort32(double d) {
  uint32_t u = __float_as_uint((float)d);
  return ((int)u < 0) ? ~u : (u | 0x80000000u);
}
__device__ __forceinline__ uint64_t sort64(double d) {
  uint64_t u = (uint64_t)__double_as_longlong(d);
  return ((long long)u < 0) ? ~u : (u | 0x8000000000000000ull);
}

// ---------------- top-k: histogram / edge / compact / sort ----------------
__global__ __launch_bounds__(256) void k_hist(const double* __restrict__ logits,
                                              uint32_t* __restrict__ hist) {
  int i = blockIdx.x * 256 + threadIdx.x;
  if (i < N_ANCH) atomicAdd(&hist[sort32(logits[i]) >> 16], 1u);
}

__global__ __launch_bounds__(1024) void k_edge(const uint32_t* __restrict__ hist,
                                               uint32_t* __restrict__ cnts) {
  __shared__ uint32_t cs[1024];
  __shared__ uint32_t g_grp, g_suf;
  int t = threadIdx.x, wv = t >> 6, ln = t & 63;
  // group sums: wave wv, round r handles group g = r*16+wv; lane-coalesced
#pragma unroll 4
  for (int r = 0; r < 64; ++r) {
    int g = r * 16 + wv;
    uint32_t x = hist[g * 64 + ln];
#pragma unroll
    for (int off = 32; off > 0; off >>= 1) x += __shfl_down(x, off);
    if (ln == 0) cs[g] = x;
  }
  __syncthreads();
  for (int off = 1; off < 1024; off <<= 1) {
    uint32_t v = cs[t] + ((t + off < 1024) ? cs[t + off] : 0u);
    __syncthreads();
    cs[t] = v;
    __syncthreads();
  }
  uint32_t sufnext = (t < 1023) ? cs[t + 1] : 0u;
  if (cs[t] >= PRE_NMS && sufnext < PRE_NMS) {   // unique t
    g_grp = (uint32_t)t;
    g_suf = sufnext;
  }
  __syncthreads();
  if (t < 64) {   // wave 0: refine edge within the winning 64-bin group
    uint32_t grp = g_grp, suf = g_suf;
    uint32_t x = hist[grp * 64 + t];
    uint32_t S = x;   // inclusive suffix sum within wave
#pragma unroll
    for (int off = 1; off < 64; off <<= 1) {
      uint32_t y = __shfl_down(S, off);
      if (t + off < 64) S += y;
    }
    unsigned long long mask = __ballot(suf + S >= PRE_NMS);
    int hi = 63 - (int)__clzll(mask);      // largest b with run >= PRE_NMS
    if (t == hi) cnts[1] = grp * 64 + (uint32_t)hi;
  }
}

__global__ __launch_bounds__(256) void k_compact(const double* __restrict__ logits,
                                                 uint32_t* __restrict__ cnts,
                                                 uint64_t* __restrict__ pkey) {
  int i = blockIdx.x * 256 + threadIdx.x;
  if (i >= N_ANCH) return;
  double lg = logits[i];
  if ((sort32(lg) >> 16) >= cnts[1]) {
    uint32_t pos = atomicAdd(&cnts[0], 1u);
    if (pos < POOL_CAP) {
      // top-47 bits of sortable score; low 17 bits encode inverted index ->
      // descending sort breaks score ties by ascending index, like top_k
      pkey[pos] = (sort64(lg) & ~0x1FFFFull) | (uint64_t)(0x1FFFFu - (uint32_t)i);
    }
  }
}

__global__ __launch_bounds__(1024) void k_sort(const uint32_t* __restrict__ cnts,
                                               const uint64_t* __restrict__ pkey,
                                               const double* __restrict__ logits,
                                               const double* __restrict__ deltas,
                                               const float* __restrict__ im_info,
                                               double* __restrict__ ss,
                                               double* __restrict__ sbx) {
  __shared__ uint64_t key[SORT_N];   // 64 KB
  int t = threadIdx.x;
  int cnt = (int)cnts[0];
  if (cnt > POOL_CAP) cnt = POOL_CAP;
  for (int e = t; e < SORT_N; e += 1024) key[e] = (e < cnt) ? pkey[e] : 0ull;
  __syncthreads();
  for (int k = 2; k <= SORT_N; k <<= 1) {
    for (int j = k >> 1; j > 0; j >>= 1) {
      for (int e = t; e < SORT_N; e += 1024) {
        int x = e ^ j;
        if (x > e) {
          uint64_t a = key[e], b = key[x];
          bool inv = (e & k) != 0;
          if (inv ? (a > b) : (a < b)) { key[e] = b; key[x] = a; }  // descending
        }
      }
      __syncthreads();
    }
  }
  double imW1 = (double)im_info[1] - 1.0;
  double imH1 = (double)im_info[0] - 1.0;
  for (int r = t; r < NMS_BLKS * 64; r += 1024) {
    if (r < PRE_NMS) {
      int gi = 0x1FFFF - (int)(key[r] & 0x1FFFFull);
      int L = 0;
      while (L < 4 && gi >= LV_AOFF[L + 1]) ++L;
      int rel = gi - LV_AOFF[L];
      int pix = rel / 3, a = rel % 3;
      int W = LV_W[L];
      int h = pix / W, w = pix % W;
      double shx = (double)(w * LV_STRIDE[L]), shy = (double)(h * LV_STRIDE[L]);
      double ax1 = BASE_ANCH[L][a][0] + shx, ay1 = BASE_ANCH[L][a][1] + shy;
      double ax2 = BASE_ANCH[L][a][2] + shx, ay2 = BASE_ANCH[L][a][3] + shy;
      double dx = deltas[gi * 4 + 0], dy = deltas[gi * 4 + 1];
      double dw = deltas[gi * 4 + 2], dh = deltas[gi * 4 + 3];
      double wa = ax2 - ax1 + 1.0, ha = ay2 - ay1 + 1.0;
      double cx = ax1 + 0.5 * wa, cy = ay1 + 0.5 * ha;
      double pcx = dx * wa + cx, pcy = dy * ha + cy;
      double pw = exp(dw) * wa, ph = exp(dh) * ha;
      double x1 = fmin(fmax(pcx - 0.5 * pw, 0.0), imW1);
      double y1 = fmin(fmax(pcy - 0.5 * ph, 0.0), imH1);
      double x2 = fmin(fmax(pcx + 0.5 * pw, 0.0), imW1);
      double y2 = fmin(fmax(pcy + 0.5 * ph, 0.0), imH1);
      ss[r] = 1.0 / (1.0 + exp(-logits[gi]));
      sbx[r * 4 + 0] = x1; sbx[r * 4 + 1] = y1;
      sbx[r * 4 + 2] = x2; sbx[r * 4 + 3] = y2;
    } else {
      ss[r] = -1.0;
#pragma unroll
      for (int c = 0; c < 4; ++c) sbx[r * 4 + c] = 0.0;
    }
  }
}

// ---------------- NMS ----------------
__device__ __forceinline__ bool iou_gt(const double* A, const double* B) {
  double areaA = (A[2] - A[0] + 1.0) * (A[3] - A[1] + 1.0);
  double areaB = (B[2] - B[0] + 1.0) * (B[3] - B[1] + 1.0);
  double xx1 = fmax(A[0], B[0]), yy1 = fmax(A[1], B[1]);
  double xx2 = fmin(A[2], B[2]), yy2 = fmin(A[3], B[3]);
  double iw = fmax(0.0, xx2 - xx1 + 1.0), ih = fmax(0.0, yy2 - yy1 + 1.0);
  double inter = iw * ih;
  return inter > 0.7 * (areaA + areaB - inter);   // union>0 always (w,h>=1)
}

__global__ __launch_bounds__(1024) void k_nms(const double* __restrict__ ss,
                                              const double* __restrict__ sbx,
                                              float* __restrict__ out) {
  __shared__ double kb[POST_NMS][4];
  __shared__ double ksc[POST_NMS];
  __shared__ double cur[64][4];
  __shared__ double csc[64];
  __shared__ unsigned int ext[64];
  __shared__ unsigned long long lrow[64];
  __shared__ unsigned long long keepmask;
  __shared__ int kcnt;
  int t = threadIdx.x;
  if (t == 0) kcnt = 0;
  __syncthreads();
  for (int b = 0; b < NMS_BLKS; ++b) {
    int i = b * 64 + t;
    if (t < 64) {
#pragma unroll
      for (int c = 0; c < 4; ++c) cur[t][c] = sbx[i * 4 + c];
      csc[t] = ss[i];
      ext[t] = (i >= PRE_NMS) ? 1u : 0u;
      lrow[t] = 0ull;
    }
    __syncthreads();
    int K = kcnt;
    for (int p = t; p < K * 64; p += 1024) {
      int k = p >> 6, ii = p & 63;
      if (!ext[ii]) {
        if (iou_gt(kb[k], cur[ii])) ext[ii] = 1u;   // benign same-value race
      }
    }
    {   // local 64x64 suppression matrix, 4 cols per thread
      int i0 = t & 63, q = t >> 6;
      unsigned long long bits = 0ull;
#pragma unroll
      for (int jj = 0; jj < 4; ++jj) {
        int j = q * 4 + jj;
        if (j > i0 && iou_gt(cur[i0], cur[j])) bits |= 1ull << j;
      }
      if (bits) atomicOr(&lrow[i0], bits);
    }
    __syncthreads();
    if (t < 64) {   // wave 0: serial bitmask scan
      unsigned long long myrow = lrow[t];
      unsigned long long extm = __ballot(ext[t] != 0u);
      unsigned long long rm = 0ull, kp = 0ull;
      for (int i2 = 0; i2 < 64; ++i2) {
        unsigned long long row = __shfl(myrow, i2);
        if (!(((rm >> i2) & 1ull) | ((extm >> i2) & 1ull))) {
          rm |= row;
          kp |= 1ull << i2;
        }
      }
      if (t == 0) keepmask = kp;
    }
    __syncthreads();
    unsigned long long kp = keepmask;
    int K0 = kcnt;
    int avail = POST_NMS - K0;
    if (t < 64 && ((kp >> t) & 1ull)) {
      int r = __popcll(kp & ((1ull << t) - 1ull));
      if (r < avail) {
        int slot = K0 + r;
#pragma unroll
        for (int c = 0; c < 4; ++c) kb[slot][c] = cur[t][c];
        ksc[slot] = csc[t];
      }
    }
    __syncthreads();
    if (t == 0) {
      int nk = __popcll(kp);
      kcnt = (K0 + nk > POST_NMS) ? POST_NMS : K0 + nk;
    }
    __syncthreads();
    if (kcnt >= POST_NMS) break;
  }
  int KF = kcnt;
  for (int r = t; r < POST_NMS; r += 1024) {
    float* o = out + r * 6;
    if (r < KF) {
      o[0] = 0.f;
      o[1] = (float)kb[r][0];
      o[2] = (float)kb[r][1];
      o[3] = (float)kb[r][2];
      o[4] = (float)kb[r][3];
      o[5] = (float)ksc[r];
    } else {
#pragma unroll
      for (int c = 0; c < 6; ++c) o[c] = 0.f;
    }
  }
}

// ---------------- host launch ----------------
extern "C" void kernel_launch(void* const* d_in, const int* in_sizes, int n_in,
                              void* d_out, int out_size, void* d_ws, size_t ws_size,
                              hipStream_t stream) {
  const float* p0 = (const float*)d_in[0];
  const float* p1 = (const float*)d_in[1];
  const float* p2 = (const float*)d_in[2];
  const float* p3 = (const float*)d_in[3];
  const float* p4 = (const float*)d_in[4];
  const float* im_info = (const float*)d_in[5];
  const float* cw = (const float*)d_in[6];
  const float* cb = (const float*)d_in[7];
  const float* sw = (const float*)d_in[8];
  const float* sb = (const float*)d_in[9];
  const float* bw = (const float*)d_in[10];
  const float* bb = (const float*)d_in[11];
  char* ws = (char*)d_ws;
  // ws layout (bytes):
  uint32_t* hist  = (uint32_t*)(ws + 0);         // 65536 u32 -> 262144
  uint32_t* cnts  = (uint32_t*)(ws + 262144);    // 256 B     -> 262400
  double*  fb     = (double*)  (ws + 262400);    // 16 f64    -> 262528
  double*  logits = (double*)  (ws + 262528);    // 106392 f64 -> 1113664
  double*  deltas = (double*)  (ws + 1113664);   // 425568 f64 -> 4518208
  double*  comb   = (double*)  (ws + 4518208);   // 512*16 f64 -> 4583744
  double*  Weff   = (double*)  (ws + 4583744);   // 2304*16 f64 -> 4878656
  double*  Wpart  = (double*)  (ws + 4878656);   // 16*2304*16 f64 -> 9597248
  uint64_t* pkey  = (uint64_t*)(ws + 9597248);   // 8192 u64  -> 9662784
  double*  ssort  = (double*)  (ws + 9662784);   // 6016 f64  -> 9710912
  double*  sbx    = (double*)  (ws + 9710912);   // 6016*4 f64 -> 9903424
  float* out = (float*)d_out;

  hipMemsetAsync(ws, 0, 262656, stream);                 // hist + counters
  k_comb<<<2, 256, 0, stream>>>(sw, bw, comb);
  k_weff_part<<<144, 256, 0, stream>>>(cw, comb, Wpart); // 16 chunks x 9 t-blocks
  k_weff_red<<<9, 256, 0, stream>>>(Wpart, Weff);
  k_bias<<<1, 256, 0, stream>>>(cb, sb, bb, comb, fb);
  k_conv15<<<555, 256, 0, stream>>>(p0, p1, p2, p3, p4, Weff, fb, logits, deltas);
  k_hist<<<416, 256, 0, stream>>>(logits, hist);
  k_edge<<<1, 1024, 0, stream>>>(hist, cnts);
  k_compact<<<416, 256, 0, stream>>>(logits, cnts, pkey);
  k_sort<<<1, 1024, 0, stream>>>(cnts, pkey, logits, deltas, im_info, ssort, sbx);
  k_nms<<<1, 1024, 0, stream>>>(ssort, sbx, out);
}

// Round 5
// 871.245 us; speedup vs baseline: 25.5162x; 1.2585x over previous
//
#include <hip/hip_runtime.h>
#include <stdint.h>

#define N_ANCH   106392
#define PRE_NMS  6000
#define POST_NMS 1000
#define POOL_CAP 8192
#define SORT_N   8192
#define NMS_BLKS 94   // 94*64 = 6016 >= 6000

static __device__ const int    LV_H[5]      = {128, 64, 32, 16, 8};
static __device__ const int    LV_W[5]      = {208, 104, 52, 26, 13};
static __device__ const int    LV_STRIDE[5] = {4, 8, 16, 32, 64};
static __device__ const int    LV_PIX[5]    = {26624, 6656, 1664, 416, 104};
static __device__ const int    LV_TILE0[6]  = {0, 416, 520, 546, 553, 555};
static __device__ const int    LV_AOFF[6]   = {0, 79872, 99840, 104832, 106080, 106392};
static __device__ const int    GPOFF[6]     = {0, 26624, 33280, 34944, 35360, 35464};
// Base anchors computed with np.round (half-even) semantics, verified by hand.
static __device__ const double BASE_ANCH[5][3][4] = {
  {{-22.,-10.,25.,13.},   {-14.,-14.,17.,17.},    {-10.,-22.,13.,25.}},
  {{-40.,-20.,47.,27.},   {-28.,-28.,35.,35.},    {-20.,-44.,27.,51.}},
  {{-84.,-40.,99.,55.},   {-56.,-56.,71.,71.},    {-36.,-80.,51.,95.}},
  {{-164.,-72.,195.,103.},{-112.,-112.,143.,143.},{-76.,-168.,107.,199.}},
  {{-332.,-152.,395.,215.},{-224.,-224.,287.,287.},{-148.,-328.,211.,391.}}
};

// sortable mappings (monotone): bigger value -> bigger key
__device__ __forceinline__ uint32_t sort32f(float f) {
  uint32_t u = __float_as_uint(f);
  return ((int)u < 0) ? ~u : (u | 0x80000000u);
}
__device__ __forceinline__ uint64_t sort64(double d) {
  uint64_t u = (uint64_t)__double_as_longlong(d);
  return ((long long)u < 0) ? ~u : (u | 0x8000000000000000ull);
}

// ---------------- f32 screen weights: w3[t][4] = score-diff fold ----------------
// blocks 0..8: w3[t*4+j] = sum_c cw[c*2304+t] * (sw[(3+j)*512+c]-sw[j*512+c])
// block 9:     fb32[j]   = sum_c cb[c] * (...) + (sb[3+j]-sb[j])
__global__ __launch_bounds__(256) void k_w3(const float* __restrict__ sw,
                                            const float* __restrict__ cw,
                                            const float* __restrict__ cb,
                                            const float* __restrict__ sb,
                                            float* __restrict__ w3,
                                            float* __restrict__ fb32) {
  if (blockIdx.x == 9) {
    int j = threadIdx.x;
    if (j < 3) {
      float s = 0.f;
      for (int c = 0; c < 512; ++c)
        s += cb[c] * (sw[(3 + j) * 512 + c] - sw[j * 512 + c]);
      fb32[j] = s + (sb[3 + j] - sb[j]);
    }
    if (j == 3) fb32[3] = 0.f;
    return;
  }
  int t = blockIdx.x * 256 + threadIdx.x;
  float a0 = 0.f, a1 = 0.f, a2 = 0.f;
#pragma unroll 1
  for (int c = 0; c < 512; ++c) {
    float v = cw[c * 2304 + t];
    a0 += v * (sw[3 * 512 + c] - sw[0 * 512 + c]);
    a1 += v * (sw[4 * 512 + c] - sw[1 * 512 + c]);
    a2 += v * (sw[5 * 512 + c] - sw[2 * 512 + c]);
  }
  w3[t * 4 + 0] = a0; w3[t * 4 + 1] = a1; w3[t * 4 + 2] = a2; w3[t * 4 + 3] = 0.f;
}

// ---------------- f64 effective weights (for refine), 2-stage ----------------
// comb inline: j<3 -> sw[3+j][c]-sw[j][c]; 3<=j<15 -> bw[j-3][c]
__device__ __forceinline__ double combf(const float* sw, const float* bw, int c, int j) {
  if (j < 3) return (double)sw[(3 + j) * 512 + c] - (double)sw[j * 512 + c];
  return (double)bw[(j - 3) * 512 + c];
}

__global__ __launch_bounds__(256) void k_weff_part(const float* __restrict__ cw,
                                                   const float* __restrict__ sw,
                                                   const float* __restrict__ bw,
                                                   double* __restrict__ Wpart) {
  int chunk = blockIdx.x / 9;            // 16 chunks of 32 channels
  int tb = blockIdx.x % 9;               // 9 t-blocks of 256
  int t = tb * 256 + threadIdx.x;        // 0..2303
  int c0 = chunk * 32;
  double acc[15];
#pragma unroll
  for (int j = 0; j < 15; ++j) acc[j] = 0.0;
#pragma unroll 1
  for (int c = c0; c < c0 + 32; ++c) {
    double v = (double)cw[c * 2304 + t];
#pragma unroll
    for (int j = 0; j < 15; ++j) acc[j] += v * combf(sw, bw, c, j);
  }
  double* o = Wpart + (((size_t)chunk * 2304 + t) << 4);
#pragma unroll
  for (int j = 0; j < 15; ++j) o[j] = acc[j];
  o[15] = 0.0;
}

// blocks 0..8: Weff[t][j] = sum over chunks (ascending); block 9: fb f64
__global__ __launch_bounds__(256) void k_weff_fin(const double* __restrict__ Wpart,
                                                  const float* __restrict__ cb,
                                                  const float* __restrict__ sb,
                                                  const float* __restrict__ bb,
                                                  const float* __restrict__ sw,
                                                  const float* __restrict__ bw,
                                                  double* __restrict__ Weff,
                                                  double* __restrict__ fb) {
  if (blockIdx.x == 9) {
    __shared__ double ps[15][16];
    int tid = threadIdx.x;
    if (tid < 240) {
      int j = tid >> 4, part = tid & 15;
      double s = 0.0;
      for (int c = part * 32; c < part * 32 + 32; ++c)
        s += (double)cb[c] * combf(sw, bw, c, j);
      ps[j][part] = s;
    }
    __syncthreads();
    if (tid < 15) {
      double s = 0.0;
#pragma unroll
      for (int part = 0; part < 16; ++part) s += ps[tid][part];  // fixed order
      s += (tid < 3) ? ((double)sb[3 + tid] - (double)sb[tid]) : (double)bb[tid - 3];
      fb[tid] = s;
    }
    return;
  }
  int t = blockIdx.x * 256 + threadIdx.x;
  double acc[15];
#pragma unroll
  for (int j = 0; j < 15; ++j) acc[j] = 0.0;
#pragma unroll 1
  for (int chunk = 0; chunk < 16; ++chunk) {
    const double* p = Wpart + (((size_t)chunk * 2304 + t) << 4);
#pragma unroll
    for (int j = 0; j < 15; ++j) acc[j] += p[j];
  }
  double* o = Weff + ((size_t)t << 4);
#pragma unroll
  for (int j = 0; j < 15; ++j) o[j] = acc[j];
  o[15] = 0.0;
}

// ---------------- f32 screening pass: 3 logits/pixel + histogram ----------------
__device__ __forceinline__ void load9(float v[9], const float* __restrict__ ib,
                                      const bool rok[3], const bool cok[3],
                                      const int roff[3]) {
#pragma unroll
  for (int ky = 0; ky < 3; ++ky)
#pragma unroll
    for (int kx = 0; kx < 3; ++kx)
      v[ky * 3 + kx] = (rok[ky] && cok[kx]) ? ib[roff[ky] + kx] : 0.0f;
}

__global__ __launch_bounds__(256) void k_fast(
    const float* __restrict__ p0, const float* __restrict__ p1,
    const float* __restrict__ p2, const float* __restrict__ p3,
    const float* __restrict__ p4,
    const float4* __restrict__ w3, const float* __restrict__ fb32,
    float* __restrict__ logits32, uint32_t* __restrict__ hist) {
  __shared__ float4 w3s[2304];       // 36.9 KB, LDS-resident weights
  __shared__ float red[4][64][3];
  int tid = threadIdx.x, wv = tid >> 6, ln = tid & 63;
  for (int i = tid; i < 2304; i += 256) w3s[i] = w3[i];
  int t = blockIdx.x;
  int L = 0;
  while (L < 4 && t >= LV_TILE0[L + 1]) ++L;
  const float* inL = (L == 0) ? p0 : (L == 1) ? p1 : (L == 2) ? p2 : (L == 3) ? p3 : p4;
  int H = LV_H[L], W = LV_W[L], HW = H * W, PIX = LV_PIX[L];
  int pix = (t - LV_TILE0[L]) * 64 + ln;
  bool valid = pix < PIX;
  if (!valid) pix = PIX - 1;
  int h = pix / W, w = pix % W;
  bool rok[3], cok[3];
  int roff[3];
#pragma unroll
  for (int ky = 0; ky < 3; ++ky) {
    int iy = h + ky - 1;
    rok[ky] = (iy >= 0 && iy < H);
    roff[ky] = iy * W + w - 1;
  }
#pragma unroll
  for (int kx = 0; kx < 3; ++kx) {
    int ix = w + kx - 1;
    cok[kx] = (ix >= 0 && ix < W);
  }
  __syncthreads();
  float a0 = 0.f, a1 = 0.f, a2 = 0.f;
  int ci0 = wv * 64;
  const float* ib = inL + ci0 * HW;
#pragma unroll 1
  for (int ci = ci0; ci < ci0 + 64; ++ci, ib += HW) {
    float v[9];
    load9(v, ib, rok, cok, roff);
    const float4* wr = w3s + ci * 9;
#pragma unroll
    for (int t9 = 0; t9 < 9; ++t9) {
      float4 wt = wr[t9];                  // broadcast ds_read_b128
      float vv = v[t9];
      a0 += vv * wt.x; a1 += vv * wt.y; a2 += vv * wt.z;
    }
  }
  red[wv][ln][0] = a0; red[wv][ln][1] = a1; red[wv][ln][2] = a2;
  __syncthreads();
  if (wv == 0 && valid) {
    int gbase = LV_AOFF[L] + pix * 3;
#pragma unroll
    for (int a = 0; a < 3; ++a) {
      float f = (red[0][ln][a] + red[1][ln][a]) + (red[2][ln][a] + red[3][ln][a]);
      f += fb32[a];
      logits32[gbase + a] = f;
      atomicAdd(&hist[sort32f(f) >> 16], 1u);
    }
  }
}

// ---------------- edge finder (with 2-bin safety margin) ----------------
__global__ __launch_bounds__(1024) void k_edge(const uint32_t* __restrict__ hist,
                                               uint32_t* __restrict__ cnts) {
  __shared__ uint32_t cs[1024];
  __shared__ uint32_t g_grp, g_suf;
  int t = threadIdx.x, wv = t >> 6, ln = t & 63;
#pragma unroll 4
  for (int r = 0; r < 64; ++r) {
    int g = r * 16 + wv;
    uint32_t x = hist[g * 64 + ln];
#pragma unroll
    for (int off = 32; off > 0; off >>= 1) x += __shfl_down(x, off);
    if (ln == 0) cs[g] = x;
  }
  __syncthreads();
  for (int off = 1; off < 1024; off <<= 1) {
    uint32_t v = cs[t] + ((t + off < 1024) ? cs[t + off] : 0u);
    __syncthreads();
    cs[t] = v;
    __syncthreads();
  }
  uint32_t sufnext = (t < 1023) ? cs[t + 1] : 0u;
  if (cs[t] >= PRE_NMS && sufnext < PRE_NMS) {   // unique t
    g_grp = (uint32_t)t;
    g_suf = sufnext;
  }
  __syncthreads();
  if (t < 64) {   // wave 0: refine edge within the winning 64-bin group
    uint32_t grp = g_grp, suf = g_suf;
    uint32_t x = hist[grp * 64 + t];
    uint32_t S = x;
#pragma unroll
    for (int off = 1; off < 64; off <<= 1) {
      uint32_t y = __shfl_down(S, off);
      if (t + off < 64) S += y;
    }
    unsigned long long mask = __ballot(suf + S >= PRE_NMS);
    int hi = 63 - (int)__clzll(mask);
    if (t == hi) {
      uint32_t e = grp * 64 + (uint32_t)hi;
      cnts[1] = (e > 2) ? e - 2 : 0;     // -2 bin margin: f32 superset of f64 top-k
    }
  }
}

// ---------------- pool compaction (f32 screen) ----------------
__global__ __launch_bounds__(256) void k_compact(const float* __restrict__ logits32,
                                                 uint32_t* __restrict__ cnts,
                                                 uint32_t* __restrict__ alist) {
  int i = blockIdx.x * 256 + threadIdx.x;
  if (i >= N_ANCH) return;
  if ((sort32f(logits32[i]) >> 16) >= cnts[1]) {
    uint32_t pos = atomicAdd(&cnts[0], 1u);
    if (pos < POOL_CAP) alist[pos] = (uint32_t)i;
  }
}

// ---------------- f64 refine: exact logit + deltas for pool anchors ----------------
__global__ __launch_bounds__(256) void k_refine(
    const float* __restrict__ p0, const float* __restrict__ p1,
    const float* __restrict__ p2, const float* __restrict__ p3,
    const float* __restrict__ p4,
    const double* __restrict__ Weff, const double* __restrict__ fb,
    const uint32_t* __restrict__ alist, const uint32_t* __restrict__ cnts,
    double* __restrict__ logits, double* __restrict__ deltas) {
  __shared__ double red[4][64][5];
  int tid = threadIdx.x, wv = tid >> 6, ln = tid & 63;
  int cnt = (int)cnts[0];
  if (cnt > POOL_CAP) cnt = POOL_CAP;
  int base = blockIdx.x * 64;
  if (base >= cnt) return;                 // uniform early-exit
  int slot = base + ln;
  if (slot >= cnt) slot = cnt - 1;         // dup tail (benign same-value writes)
  int gi = (int)alist[slot];
  int gpix = gi / 3, a = gi - gpix * 3;
  int L = 0;
  while (L < 4 && gpix >= GPOFF[L + 1]) ++L;
  int pix = gpix - GPOFF[L];
  const float* inL = (L == 0) ? p0 : (L == 1) ? p1 : (L == 2) ? p2 : (L == 3) ? p3 : p4;
  int H = LV_H[L], W = LV_W[L], HW = H * W;
  int h = pix / W, w = pix % W;
  bool rok[3], cok[3];
  int roff[3];
#pragma unroll
  for (int ky = 0; ky < 3; ++ky) {
    int iy = h + ky - 1;
    rok[ky] = (iy >= 0 && iy < H);
    roff[ky] = iy * W + w - 1;
  }
#pragma unroll
  for (int kx = 0; kx < 3; ++kx) {
    int ix = w + kx - 1;
    cok[kx] = (ix >= 0 && ix < W);
  }
  double sc = 0.0, d0 = 0.0, d1 = 0.0, d2 = 0.0, d3 = 0.0;
  int js = a, jd = 3 + 4 * a;
  int ci0 = wv * 64;
  const float* ib = inL + ci0 * HW;
#pragma unroll 1
  for (int ci = ci0; ci < ci0 + 64; ++ci, ib += HW) {
    float v[9];
    load9(v, ib, rok, cok, roff);
    const double* wr = Weff + ((size_t)ci * 144);
#pragma unroll
    for (int t9 = 0; t9 < 9; ++t9) {
      double vd = (double)v[t9];
      const double* wt = wr + t9 * 16;
      sc += vd * wt[js];
      d0 += vd * wt[jd + 0];
      d1 += vd * wt[jd + 1];
      d2 += vd * wt[jd + 2];
      d3 += vd * wt[jd + 3];
    }
  }
  red[wv][ln][0] = sc;
  red[wv][ln][1] = d0; red[wv][ln][2] = d1;
  red[wv][ln][3] = d2; red[wv][ln][4] = d3;
  __syncthreads();
  if (wv == 0) {
    double f[5];
#pragma unroll
    for (int j = 0; j < 5; ++j)
      f[j] = red[0][ln][j] + red[1][ln][j] + red[2][ln][j] + red[3][ln][j];
    logits[gi] = f[0] + fb[js];
    deltas[gi * 4 + 0] = f[1] + fb[jd + 0];
    deltas[gi * 4 + 1] = f[2] + fb[jd + 1];
    deltas[gi * 4 + 2] = f[3] + fb[jd + 2];
    deltas[gi * 4 + 3] = f[4] + fb[jd + 3];
  }
}

// ---------------- sort (keys built inline from refined f64 logits) ----------------
__global__ __launch_bounds__(1024) void k_sort(const uint32_t* __restrict__ cnts,
                                               const uint32_t* __restrict__ alist,
                                               const double* __restrict__ logits,
                                               const double* __restrict__ deltas,
                                               const float* __restrict__ im_info,
                                               double* __restrict__ ss,
                                               double* __restrict__ sbx) {
  __shared__ uint64_t key[SORT_N];   // 64 KB
  int t = threadIdx.x;
  int cnt = (int)cnts[0];
  if (cnt > POOL_CAP) cnt = POOL_CAP;
  for (int e = t; e < SORT_N; e += 1024) {
    uint64_t k = 0ull;
    if (e < cnt) {
      int gi = (int)alist[e];
      // top-47 bits of sortable f64 logit; low 17 bits inverted index ->
      // descending sort breaks score ties by ascending index (top_k semantics)
      k = (sort64(logits[gi]) & ~0x1FFFFull) | (uint64_t)(0x1FFFFu - (uint32_t)gi);
    }
    key[e] = k;
  }
  __syncthreads();
  for (int k = 2; k <= SORT_N; k <<= 1) {
    for (int j = k >> 1; j > 0; j >>= 1) {
      for (int e = t; e < SORT_N; e += 1024) {
        int x = e ^ j;
        if (x > e) {
          uint64_t a = key[e], b = key[x];
          bool inv = (e & k) != 0;
          if (inv ? (a > b) : (a < b)) { key[e] = b; key[x] = a; }  // descending
        }
      }
      __syncthreads();
    }
  }
  double imW1 = (double)im_info[1] - 1.0;
  double imH1 = (double)im_info[0] - 1.0;
  for (int r = t; r < NMS_BLKS * 64; r += 1024) {
    if (r < PRE_NMS) {
      int gi = 0x1FFFF - (int)(key[r] & 0x1FFFFull);
      int L = 0;
      while (L < 4 && gi >= LV_AOFF[L + 1]) ++L;
      int rel = gi - LV_AOFF[L];
      int pix = rel / 3, a = rel % 3;
      int W = LV_W[L];
      int h = pix / W, w = pix % W;
      double shx = (double)(w * LV_STRIDE[L]), shy = (double)(h * LV_STRIDE[L]);
      double ax1 = BASE_ANCH[L][a][0] + shx, ay1 = BASE_ANCH[L][a][1] + shy;
      double ax2 = BASE_ANCH[L][a][2] + shx, ay2 = BASE_ANCH[L][a][3] + shy;
      double dx = deltas[gi * 4 + 0], dy = deltas[gi * 4 + 1];
      double dw = deltas[gi * 4 + 2], dh = deltas[gi * 4 + 3];
      double wa = ax2 - ax1 + 1.0, ha = ay2 - ay1 + 1.0;
      double cx = ax1 + 0.5 * wa, cy = ay1 + 0.5 * ha;
      double pcx = dx * wa + cx, pcy = dy * ha + cy;
      double pw = exp(dw) * wa, ph = exp(dh) * ha;
      double x1 = fmin(fmax(pcx - 0.5 * pw, 0.0), imW1);
      double y1 = fmin(fmax(pcy - 0.5 * ph, 0.0), imH1);
      double x2 = fmin(fmax(pcx + 0.5 * pw, 0.0), imW1);
      double y2 = fmin(fmax(pcy + 0.5 * ph, 0.0), imH1);
      ss[r] = 1.0 / (1.0 + exp(-logits[gi]));
      sbx[r * 4 + 0] = x1; sbx[r * 4 + 1] = y1;
      sbx[r * 4 + 2] = x2; sbx[r * 4 + 3] = y2;
    } else {
      ss[r] = -1.0;
#pragma unroll
      for (int c = 0; c < 4; ++c) sbx[r * 4 + c] = 0.0;
    }
  }
}

// ---------------- NMS ----------------
__device__ __forceinline__ bool iou_gt(const double* A, const double* B) {
  double areaA = (A[2] - A[0] + 1.0) * (A[3] - A[1] + 1.0);
  double areaB = (B[2] - B[0] + 1.0) * (B[3] - B[1] + 1.0);
  double xx1 = fmax(A[0], B[0]), yy1 = fmax(A[1], B[1]);
  double xx2 = fmin(A[2], B[2]), yy2 = fmin(A[3], B[3]);
  double iw = fmax(0.0, xx2 - xx1 + 1.0), ih = fmax(0.0, yy2 - yy1 + 1.0);
  double inter = iw * ih;
  return inter > 0.7 * (areaA + areaB - inter);
}

__global__ __launch_bounds__(1024) void k_nms(const double* __restrict__ ss,
                                              const double* __restrict__ sbx,
                                              float* __restrict__ out) {
  __shared__ double kb[POST_NMS][4];
  __shared__ double ksc[POST_NMS];
  __shared__ double cur[64][4];
  __shared__ double csc[64];
  __shared__ unsigned int ext[64];
  __shared__ unsigned long long lrow[64];
  __shared__ unsigned long long keepmask;
  __shared__ int kcnt;
  int t = threadIdx.x;
  if (t == 0) kcnt = 0;
  __syncthreads();
  for (int b = 0; b < NMS_BLKS; ++b) {
    int i = b * 64 + t;
    if (t < 64) {
#pragma unroll
      for (int c = 0; c < 4; ++c) cur[t][c] = sbx[i * 4 + c];
      csc[t] = ss[i];
      ext[t] = (i >= PRE_NMS) ? 1u : 0u;
      lrow[t] = 0ull;
    }
    __syncthreads();
    int K = kcnt;
    for (int p = t; p < K * 64; p += 1024) {
      int k = p >> 6, ii = p & 63;
      if (!ext[ii]) {
        if (iou_gt(kb[k], cur[ii])) ext[ii] = 1u;
      }
    }
    {
      int i0 = t & 63, q = t >> 6;
      unsigned long long bits = 0ull;
#pragma unroll
      for (int jj = 0; jj < 4; ++jj) {
        int j = q * 4 + jj;
        if (j > i0 && iou_gt(cur[i0], cur[j])) bits |= 1ull << j;
      }
      if (bits) atomicOr(&lrow[i0], bits);
    }
    __syncthreads();
    if (t < 64) {
      unsigned long long myrow = lrow[t];
      unsigned long long extm = __ballot(ext[t] != 0u);
      unsigned long long rm = 0ull, kp = 0ull;
      for (int i2 = 0; i2 < 64; ++i2) {
        unsigned long long row = __shfl(myrow, i2);
        if (!(((rm >> i2) & 1ull) | ((extm >> i2) & 1ull))) {
          rm |= row;
          kp |= 1ull << i2;
        }
      }
      if (t == 0) keepmask = kp;
    }
    __syncthreads();
    unsigned long long kp = keepmask;
    int K0 = kcnt;
    int avail = POST_NMS - K0;
    if (t < 64 && ((kp >> t) & 1ull)) {
      int r = __popcll(kp & ((1ull << t) - 1ull));
      if (r < avail) {
        int slot = K0 + r;
#pragma unroll
        for (int c = 0; c < 4; ++c) kb[slot][c] = cur[t][c];
        ksc[slot] = csc[t];
      }
    }
    __syncthreads();
    if (t == 0) {
      int nk = __popcll(kp);
      kcnt = (K0 + nk > POST_NMS) ? POST_NMS : K0 + nk;
    }
    __syncthreads();
    if (kcnt >= POST_NMS) break;
  }
  int KF = kcnt;
  for (int r = t; r < POST_NMS; r += 1024) {
    float* o = out + r * 6;
    if (r < KF) {
      o[0] = 0.f;
      o[1] = (float)kb[r][0];
      o[2] = (float)kb[r][1];
      o[3] = (float)kb[r][2];
      o[4] = (float)kb[r][3];
      o[5] = (float)ksc[r];
    } else {
#pragma unroll
      for (int c = 0; c < 6; ++c) o[c] = 0.f;
    }
  }
}

// ---------------- host launch ----------------
extern "C" void kernel_launch(void* const* d_in, const int* in_sizes, int n_in,
                              void* d_out, int out_size, void* d_ws, size_t ws_size,
                              hipStream_t stream) {
  const float* p0 = (const float*)d_in[0];
  const float* p1 = (const float*)d_in[1];
  const float* p2 = (const float*)d_in[2];
  const float* p3 = (const float*)d_in[3];
  const float* p4 = (const float*)d_in[4];
  const float* im_info = (const float*)d_in[5];
  const float* cw = (const float*)d_in[6];
  const float* cb = (const float*)d_in[7];
  const float* sw = (const float*)d_in[8];
  const float* sb = (const float*)d_in[9];
  const float* bw = (const float*)d_in[10];
  const float* bb = (const float*)d_in[11];
  char* ws = (char*)d_ws;
  // ws layout (bytes):
  uint32_t* hist    = (uint32_t*)(ws + 0);         // 65536 u32 -> 262144
  uint32_t* cnts    = (uint32_t*)(ws + 262144);    // 64 B: [0]=pool [1]=edge -> 262208
  double*   fb      = (double*)  (ws + 262208);    // 16 f64 -> 262336
  float*    fb32    = (float*)   (ws + 262336);    // 4 f32  -> 262352
  double*   logits  = (double*)  (ws + 262352);    // 106392 f64 -> 1113488
  double*   deltas  = (double*)  (ws + 1113488);   // 425568 f64 -> 4518032
  float*    logits32= (float*)   (ws + 4518032);   // 106392 f32 -> 4943600
  float*    w3      = (float*)   (ws + 4943600);   // 2304*4 f32 -> 4980464 (16-aligned)
  double*   Weff    = (double*)  (ws + 4980464);   // 2304*16 f64 -> 5275376
  double*   Wpart   = (double*)  (ws + 5275376);   // 16*2304*16 f64 -> 9993968
  uint32_t* alist   = (uint32_t*)(ws + 9993968);   // 8192 u32 -> 10026736
  double*   ssort   = (double*)  (ws + 10026736);  // 6016 f64 -> 10074864
  double*   sbx     = (double*)  (ws + 10074864);  // 6016*4 f64 -> 10267376
  float* out = (float*)d_out;

  hipMemsetAsync(ws, 0, 262208, stream);           // hist + counters
  k_w3<<<10, 256, 0, stream>>>(sw, cw, cb, sb, w3, fb32);
  k_fast<<<555, 256, 0, stream>>>(p0, p1, p2, p3, p4, (const float4*)w3, fb32,
                                  logits32, hist);
  k_edge<<<1, 1024, 0, stream>>>(hist, cnts);
  k_compact<<<416, 256, 0, stream>>>(logits32, cnts, alist);
  k_weff_part<<<144, 256, 0, stream>>>(cw, sw, bw, Wpart);
  k_weff_fin<<<10, 256, 0, stream>>>(Wpart, cb, sb, bb, sw, bw, Weff, fb);
  k_refine<<<128, 256, 0, stream>>>(p0, p1, p2, p3, p4, Weff, fb, alist, cnts,
                                    logits, deltas);
  k_sort<<<1, 1024, 0, stream>>>(cnts, alist, logits, deltas, im_info, ssort, sbx);
  k_nms<<<1, 1024, 0, stream>>>(ssort, sbx, out);
}

// Round 6
// 645.067 us; speedup vs baseline: 34.4628x; 1.3506x over previous
//
#include <hip/hip_runtime.h>
#include <stdint.h>

#define N_ANCH   106392
#define PRE_NMS  6000
#define POST_NMS 1000
#define POOL_CAP 8192
#define SORT_N   8192
#define NMS_BLKS 94   // 94*64 = 6016 >= 6000
#define SUP_W    96   // padded words per suppression row

static __device__ const int    LV_H[5]      = {128, 64, 32, 16, 8};
static __device__ const int    LV_W[5]      = {208, 104, 52, 26, 13};
static __device__ const int    LV_STRIDE[5] = {4, 8, 16, 32, 64};
static __device__ const int    LV_PIX[5]    = {26624, 6656, 1664, 416, 104};
static __device__ const int    LV_TILE0[6]  = {0, 416, 520, 546, 553, 555};
static __device__ const int    LV_AOFF[6]   = {0, 79872, 99840, 104832, 106080, 106392};
static __device__ const int    GPOFF[6]     = {0, 26624, 33280, 34944, 35360, 35464};
// Base anchors computed with np.round (half-even) semantics, verified by hand.
static __device__ const double BASE_ANCH[5][3][4] = {
  {{-22.,-10.,25.,13.},   {-14.,-14.,17.,17.},    {-10.,-22.,13.,25.}},
  {{-40.,-20.,47.,27.},   {-28.,-28.,35.,35.},    {-20.,-44.,27.,51.}},
  {{-84.,-40.,99.,55.},   {-56.,-56.,71.,71.},    {-36.,-80.,51.,95.}},
  {{-164.,-72.,195.,103.},{-112.,-112.,143.,143.},{-76.,-168.,107.,199.}},
  {{-332.,-152.,395.,215.},{-224.,-224.,287.,287.},{-148.,-328.,211.,391.}}
};

// sortable mappings (monotone): bigger value -> bigger key
__device__ __forceinline__ uint32_t sort32f(float f) {
  uint32_t u = __float_as_uint(f);
  return ((int)u < 0) ? ~u : (u | 0x80000000u);
}
__device__ __forceinline__ uint64_t sort64(double d) {
  uint64_t u = (uint64_t)__double_as_longlong(d);
  return ((long long)u < 0) ? ~u : (u | 0x8000000000000000ull);
}

// ---------------- f64 effective weights, 2-stage ----------------
// comb inline: j<3 -> sw[3+j][c]-sw[j][c]; 3<=j<15 -> bw[j-3][c]
__device__ __forceinline__ double combf(const float* sw, const float* bw, int c, int j) {
  if (j < 3) return (double)sw[(3 + j) * 512 + c] - (double)sw[j * 512 + c];
  return (double)bw[(j - 3) * 512 + c];
}

__global__ __launch_bounds__(256) void k_weff_part(const float* __restrict__ cw,
                                                   const float* __restrict__ sw,
                                                   const float* __restrict__ bw,
                                                   double* __restrict__ Wpart) {
  int chunk = blockIdx.x / 9;            // 16 chunks of 32 channels
  int tb = blockIdx.x % 9;               // 9 t-blocks of 256
  int t = tb * 256 + threadIdx.x;        // 0..2303
  int c0 = chunk * 32;
  double acc[15];
#pragma unroll
  for (int j = 0; j < 15; ++j) acc[j] = 0.0;
#pragma unroll 1
  for (int c = c0; c < c0 + 32; ++c) {
    double v = (double)cw[c * 2304 + t];
#pragma unroll
    for (int j = 0; j < 15; ++j) acc[j] += v * combf(sw, bw, c, j);
  }
  double* o = Wpart + (((size_t)chunk * 2304 + t) << 4);
#pragma unroll
  for (int j = 0; j < 15; ++j) o[j] = acc[j];
  o[15] = 0.0;
}

// blocks 0..8: Weff[t][j] = sum over chunks; also emit f32 screen weights w3.
// block 9: fb f64 + fb32.
__global__ __launch_bounds__(256) void k_weff_fin(const double* __restrict__ Wpart,
                                                  const float* __restrict__ cb,
                                                  const float* __restrict__ sb,
                                                  const float* __restrict__ bb,
                                                  const float* __restrict__ sw,
                                                  const float* __restrict__ bw,
                                                  double* __restrict__ Weff,
                                                  double* __restrict__ fb,
                                                  float4* __restrict__ w3,
                                                  float* __restrict__ fb32) {
  if (blockIdx.x == 9) {
    __shared__ double ps[15][16];
    int tid = threadIdx.x;
    if (tid < 240) {
      int j = tid >> 4, part = tid & 15;
      double s = 0.0;
      for (int c = part * 32; c < part * 32 + 32; ++c)
        s += (double)cb[c] * combf(sw, bw, c, j);
      ps[j][part] = s;
    }
    __syncthreads();
    if (tid < 15) {
      double s = 0.0;
#pragma unroll
      for (int part = 0; part < 16; ++part) s += ps[tid][part];  // fixed order
      s += (tid < 3) ? ((double)sb[3 + tid] - (double)sb[tid]) : (double)bb[tid - 3];
      fb[tid] = s;
      if (tid < 3) fb32[tid] = (float)s;
    }
    if (tid == 15) fb32[3] = 0.f;
    return;
  }
  int t = blockIdx.x * 256 + threadIdx.x;
  double acc[15];
#pragma unroll
  for (int j = 0; j < 15; ++j) acc[j] = 0.0;
#pragma unroll 1
  for (int chunk = 0; chunk < 16; ++chunk) {
    const double* p = Wpart + (((size_t)chunk * 2304 + t) << 4);
#pragma unroll
    for (int j = 0; j < 15; ++j) acc[j] += p[j];
  }
  double* o = Weff + ((size_t)t << 4);
#pragma unroll
  for (int j = 0; j < 15; ++j) o[j] = acc[j];
  o[15] = 0.0;
  float4 wf;
  wf.x = (float)acc[0]; wf.y = (float)acc[1]; wf.z = (float)acc[2]; wf.w = 0.f;
  w3[t] = wf;
}

// ---------------- f32 screening pass: 3 logits/pixel + histogram ----------------
__device__ __forceinline__ void load9(float v[9], const float* __restrict__ ib,
                                      const bool rok[3], const bool cok[3],
                                      const int roff[3]) {
#pragma unroll
  for (int ky = 0; ky < 3; ++ky)
#pragma unroll
    for (int kx = 0; kx < 3; ++kx)
      v[ky * 3 + kx] = (rok[ky] && cok[kx]) ? ib[roff[ky] + kx] : 0.0f;
}

__global__ __launch_bounds__(256) void k_fast(
    const float* __restrict__ p0, const float* __restrict__ p1,
    const float* __restrict__ p2, const float* __restrict__ p3,
    const float* __restrict__ p4,
    const float4* __restrict__ w3, const float* __restrict__ fb32,
    float* __restrict__ logits32, uint32_t* __restrict__ hist) {
  __shared__ float4 w3s[2304];       // 36.9 KB, LDS-resident weights
  __shared__ float red[4][64][3];
  int tid = threadIdx.x, wv = tid >> 6, ln = tid & 63;
  for (int i = tid; i < 2304; i += 256) w3s[i] = w3[i];
  int t = blockIdx.x;
  int L = 0;
  while (L < 4 && t >= LV_TILE0[L + 1]) ++L;
  const float* inL = (L == 0) ? p0 : (L == 1) ? p1 : (L == 2) ? p2 : (L == 3) ? p3 : p4;
  int H = LV_H[L], W = LV_W[L], HW = H * W, PIX = LV_PIX[L];
  int pix = (t - LV_TILE0[L]) * 64 + ln;
  bool valid = pix < PIX;
  if (!valid) pix = PIX - 1;
  int h = pix / W, w = pix % W;
  bool rok[3], cok[3];
  int roff[3];
#pragma unroll
  for (int ky = 0; ky < 3; ++ky) {
    int iy = h + ky - 1;
    rok[ky] = (iy >= 0 && iy < H);
    roff[ky] = iy * W + w - 1;
  }
#pragma unroll
  for (int kx = 0; kx < 3; ++kx) {
    int ix = w + kx - 1;
    cok[kx] = (ix >= 0 && ix < W);
  }
  __syncthreads();
  float a0 = 0.f, a1 = 0.f, a2 = 0.f;
  int ci0 = wv * 64;
  const float* ib = inL + ci0 * HW;
#pragma unroll 1
  for (int ci = ci0; ci < ci0 + 64; ++ci, ib += HW) {
    float v[9];
    load9(v, ib, rok, cok, roff);
    const float4* wr = w3s + ci * 9;
#pragma unroll
    for (int t9 = 0; t9 < 9; ++t9) {
      float4 wt = wr[t9];                  // broadcast ds_read_b128
      float vv = v[t9];
      a0 += vv * wt.x; a1 += vv * wt.y; a2 += vv * wt.z;
    }
  }
  red[wv][ln][0] = a0; red[wv][ln][1] = a1; red[wv][ln][2] = a2;
  __syncthreads();
  if (wv == 0 && valid) {
    int gbase = LV_AOFF[L] + pix * 3;
#pragma unroll
    for (int a = 0; a < 3; ++a) {
      float f = (red[0][ln][a] + red[1][ln][a]) + (red[2][ln][a] + red[3][ln][a]);
      f += fb32[a];
      logits32[gbase + a] = f;
      atomicAdd(&hist[sort32f(f) >> 16], 1u);
    }
  }
}

// ---------------- edge finder (with 2-bin safety margin) ----------------
__global__ __launch_bounds__(1024) void k_edge(const uint32_t* __restrict__ hist,
                                               uint32_t* __restrict__ cnts) {
  __shared__ uint32_t cs[1024];
  __shared__ uint32_t g_grp, g_suf;
  int t = threadIdx.x, wv = t >> 6, ln = t & 63;
#pragma unroll 4
  for (int r = 0; r < 64; ++r) {
    int g = r * 16 + wv;
    uint32_t x = hist[g * 64 + ln];
#pragma unroll
    for (int off = 32; off > 0; off >>= 1) x += __shfl_down(x, off);
    if (ln == 0) cs[g] = x;
  }
  __syncthreads();
  for (int off = 1; off < 1024; off <<= 1) {
    uint32_t v = cs[t] + ((t + off < 1024) ? cs[t + off] : 0u);
    __syncthreads();
    cs[t] = v;
    __syncthreads();
  }
  uint32_t sufnext = (t < 1023) ? cs[t + 1] : 0u;
  if (cs[t] >= PRE_NMS && sufnext < PRE_NMS) {   // unique t
    g_grp = (uint32_t)t;
    g_suf = sufnext;
  }
  __syncthreads();
  if (t < 64) {   // wave 0: refine edge within the winning 64-bin group
    uint32_t grp = g_grp, suf = g_suf;
    uint32_t x = hist[grp * 64 + t];
    uint32_t S = x;
#pragma unroll
    for (int off = 1; off < 64; off <<= 1) {
      uint32_t y = __shfl_down(S, off);
      if (t + off < 64) S += y;
    }
    unsigned long long mask = __ballot(suf + S >= PRE_NMS);
    int hi = 63 - (int)__clzll(mask);
    if (t == hi) {
      uint32_t e = grp * 64 + (uint32_t)hi;
      cnts[1] = (e > 2) ? e - 2 : 0;     // -2 bin margin: f32 superset of f64 top-k
    }
  }
}

// ---------------- pool compaction (f32 screen) ----------------
__global__ __launch_bounds__(256) void k_compact(const float* __restrict__ logits32,
                                                 uint32_t* __restrict__ cnts,
                                                 uint32_t* __restrict__ alist) {
  int i = blockIdx.x * 256 + threadIdx.x;
  if (i >= N_ANCH) return;
  if ((sort32f(logits32[i]) >> 16) >= cnts[1]) {
    uint32_t pos = atomicAdd(&cnts[0], 1u);
    if (pos < POOL_CAP) alist[pos] = (uint32_t)i;
  }
}

// ---------------- f64 refine: exact logit + deltas for pool anchors ----------------
__global__ __launch_bounds__(256) void k_refine(
    const float* __restrict__ p0, const float* __restrict__ p1,
    const float* __restrict__ p2, const float* __restrict__ p3,
    const float* __restrict__ p4,
    const double* __restrict__ Weff, const double* __restrict__ fb,
    const uint32_t* __restrict__ alist, const uint32_t* __restrict__ cnts,
    double* __restrict__ logits, double* __restrict__ deltas) {
  __shared__ double red[4][64][5];
  int tid = threadIdx.x, wv = tid >> 6, ln = tid & 63;
  int cnt = (int)cnts[0];
  if (cnt > POOL_CAP) cnt = POOL_CAP;
  int base = blockIdx.x * 64;
  if (base >= cnt) return;                 // uniform early-exit
  int slot = base + ln;
  if (slot >= cnt) slot = cnt - 1;         // dup tail (benign same-value writes)
  int gi = (int)alist[slot];
  int gpix = gi / 3, a = gi - gpix * 3;
  int L = 0;
  while (L < 4 && gpix >= GPOFF[L + 1]) ++L;
  int pix = gpix - GPOFF[L];
  const float* inL = (L == 0) ? p0 : (L == 1) ? p1 : (L == 2) ? p2 : (L == 3) ? p3 : p4;
  int H = LV_H[L], W = LV_W[L], HW = H * W;
  int h = pix / W, w = pix % W;
  bool rok[3], cok[3];
  int roff[3];
#pragma unroll
  for (int ky = 0; ky < 3; ++ky) {
    int iy = h + ky - 1;
    rok[ky] = (iy >= 0 && iy < H);
    roff[ky] = iy * W + w - 1;
  }
#pragma unroll
  for (int kx = 0; kx < 3; ++kx) {
    int ix = w + kx - 1;
    cok[kx] = (ix >= 0 && ix < W);
  }
  double sc = 0.0, d0 = 0.0, d1 = 0.0, d2 = 0.0, d3 = 0.0;
  int js = a, jd = 3 + 4 * a;
  int ci0 = wv * 64;
  const float* ib = inL + ci0 * HW;
#pragma unroll 1
  for (int ci = ci0; ci < ci0 + 64; ++ci, ib += HW) {
    float v[9];
    load9(v, ib, rok, cok, roff);
    const double* wr = Weff + ((size_t)ci * 144);
#pragma unroll
    for (int t9 = 0; t9 < 9; ++t9) {
      double vd = (double)v[t9];
      const double* wt = wr + t9 * 16;
      sc += vd * wt[js];
      d0 += vd * wt[jd + 0];
      d1 += vd * wt[jd + 1];
      d2 += vd * wt[jd + 2];
      d3 += vd * wt[jd + 3];
    }
  }
  red[wv][ln][0] = sc;
  red[wv][ln][1] = d0; red[wv][ln][2] = d1;
  red[wv][ln][3] = d2; red[wv][ln][4] = d3;
  __syncthreads();
  if (wv == 0) {
    double f[5];
#pragma unroll
    for (int j = 0; j < 5; ++j)
      f[j] = red[0][ln][j] + red[1][ln][j] + red[2][ln][j] + red[3][ln][j];
    logits[gi] = f[0] + fb[js];
    deltas[gi * 4 + 0] = f[1] + fb[jd + 0];
    deltas[gi * 4 + 1] = f[2] + fb[jd + 1];
    deltas[gi * 4 + 2] = f[3] + fb[jd + 2];
    deltas[gi * 4 + 3] = f[4] + fb[jd + 3];
  }
}

// ---------------- sort + box decode (also emits f32 boxes/areas) ----------------
__global__ __launch_bounds__(1024) void k_sort(const uint32_t* __restrict__ cnts,
                                               const uint32_t* __restrict__ alist,
                                               const double* __restrict__ logits,
                                               const double* __restrict__ deltas,
                                               const float* __restrict__ im_info,
                                               double* __restrict__ ss,
                                               double* __restrict__ sbx,
                                               float4* __restrict__ bxf,
                                               float* __restrict__ areaf) {
  __shared__ uint64_t key[SORT_N];   // 64 KB
  int t = threadIdx.x;
  int cnt = (int)cnts[0];
  if (cnt > POOL_CAP) cnt = POOL_CAP;
  for (int e = t; e < SORT_N; e += 1024) {
    uint64_t k = 0ull;
    if (e < cnt) {
      int gi = (int)alist[e];
      // top-47 bits of sortable f64 logit; low 17 bits inverted index ->
      // descending sort breaks score ties by ascending index (top_k semantics)
      k = (sort64(logits[gi]) & ~0x1FFFFull) | (uint64_t)(0x1FFFFu - (uint32_t)gi);
    }
    key[e] = k;
  }
  __syncthreads();
  for (int k = 2; k <= SORT_N; k <<= 1) {
    for (int j = k >> 1; j > 0; j >>= 1) {
      for (int e = t; e < SORT_N; e += 1024) {
        int x = e ^ j;
        if (x > e) {
          uint64_t a = key[e], b = key[x];
          bool inv = (e & k) != 0;
          if (inv ? (a > b) : (a < b)) { key[e] = b; key[x] = a; }  // descending
        }
      }
      __syncthreads();
    }
  }
  double imW1 = (double)im_info[1] - 1.0;
  double imH1 = (double)im_info[0] - 1.0;
  for (int r = t; r < NMS_BLKS * 64; r += 1024) {
    if (r < PRE_NMS) {
      int gi = 0x1FFFF - (int)(key[r] & 0x1FFFFull);
      int L = 0;
      while (L < 4 && gi >= LV_AOFF[L + 1]) ++L;
      int rel = gi - LV_AOFF[L];
      int pix = rel / 3, a = rel % 3;
      int W = LV_W[L];
      int h = pix / W, w = pix % W;
      double shx = (double)(w * LV_STRIDE[L]), shy = (double)(h * LV_STRIDE[L]);
      double ax1 = BASE_ANCH[L][a][0] + shx, ay1 = BASE_ANCH[L][a][1] + shy;
      double ax2 = BASE_ANCH[L][a][2] + shx, ay2 = BASE_ANCH[L][a][3] + shy;
      double dx = deltas[gi * 4 + 0], dy = deltas[gi * 4 + 1];
      double dw = deltas[gi * 4 + 2], dh = deltas[gi * 4 + 3];
      double wa = ax2 - ax1 + 1.0, ha = ay2 - ay1 + 1.0;
      double cx = ax1 + 0.5 * wa, cy = ay1 + 0.5 * ha;
      double pcx = dx * wa + cx, pcy = dy * ha + cy;
      double pw = exp(dw) * wa, ph = exp(dh) * ha;
      double x1 = fmin(fmax(pcx - 0.5 * pw, 0.0), imW1);
      double y1 = fmin(fmax(pcy - 0.5 * ph, 0.0), imH1);
      double x2 = fmin(fmax(pcx + 0.5 * pw, 0.0), imW1);
      double y2 = fmin(fmax(pcy + 0.5 * ph, 0.0), imH1);
      ss[r] = 1.0 / (1.0 + exp(-logits[gi]));
      sbx[r * 4 + 0] = x1; sbx[r * 4 + 1] = y1;
      sbx[r * 4 + 2] = x2; sbx[r * 4 + 3] = y2;
      float4 bf;
      bf.x = (float)x1; bf.y = (float)y1; bf.z = (float)x2; bf.w = (float)y2;
      bxf[r] = bf;
      areaf[r] = (float)((x2 - x1 + 1.0) * (y2 - y1 + 1.0));
    } else {
      ss[r] = -1.0;
#pragma unroll
      for (int c = 0; c < 4; ++c) sbx[r * 4 + c] = 0.0;
      float4 z; z.x = 0.f; z.y = 0.f; z.z = 0.f; z.w = 0.f;
      bxf[r] = z;
      areaf[r] = 0.f;
    }
  }
}

// ---------------- exact f64 IoU decision (reference semantics) ----------------
__device__ __forceinline__ bool iou_gt(const double* A, const double* B) {
  double areaA = (A[2] - A[0] + 1.0) * (A[3] - A[1] + 1.0);
  double areaB = (B[2] - B[0] + 1.0) * (B[3] - B[1] + 1.0);
  double xx1 = fmax(A[0], B[0]), yy1 = fmax(A[1], B[1]);
  double xx2 = fmin(A[2], B[2]), yy2 = fmin(A[3], B[3]);
  double iw = fmax(0.0, xx2 - xx1 + 1.0), ih = fmax(0.0, yy2 - yy1 + 1.0);
  double inter = iw * ih;
  return inter > 0.7 * (areaA + areaB - inter);
}

// ---------------- suppression matrix build (upper triangle) ----------------
// Sup[r][w] bit jj set  <=>  IoU(box r, box w*64+jj) > 0.7, for j > r.
// f32 prefilter with +-4.0 absolute margin on (inter - 0.7*union); f64 confirm
// in the gray zone -> decisions identical to pure f64.
__global__ __launch_bounds__(256) void k_build(const double* __restrict__ sbx,
                                               const float4* __restrict__ bxf,
                                               const float* __restrict__ areaf,
                                               uint64_t* __restrict__ Sup) {
  __shared__ float cbx[256][5];
  __shared__ float rbx[64][5];
  int blk = blockIdx.x;
  int rtile = blk / 24, ctile = blk % 24;   // 94 x 24
  int t = threadIdx.x, q = t >> 6, ln = t & 63;
  int r = rtile * 64 + ln;
  int w = ctile * 4 + q;                    // word 0..95
  {
    int c = ctile * 256 + t;
    float4 b;
    float ar;
    if (c < NMS_BLKS * 64) { b = bxf[c]; ar = areaf[c]; }
    else { b.x = b.y = b.z = b.w = 0.f; ar = 0.f; }
    cbx[t][0] = b.x; cbx[t][1] = b.y; cbx[t][2] = b.z; cbx[t][3] = b.w; cbx[t][4] = ar;
    if (t < 64) {
      int rr = rtile * 64 + t;
      float4 rb = bxf[rr];
      rbx[t][0] = rb.x; rbx[t][1] = rb.y; rbx[t][2] = rb.z; rbx[t][3] = rb.w;
      rbx[t][4] = areaf[rr];
    }
  }
  __syncthreads();
  uint64_t bits = 0ull;
  int j0 = w * 64;
  if (w < NMS_BLKS && j0 + 63 > r) {
    float ax1 = rbx[ln][0], ay1 = rbx[ln][1], ax2 = rbx[ln][2], ay2 = rbx[ln][3];
    float aar = rbx[ln][4];
#pragma unroll 4
    for (int jj = 0; jj < 64; ++jj) {
      int j = j0 + jj;
      if (j <= r) continue;
      int cl = q * 64 + jj;
      float iw = fminf(ax2, cbx[cl][2]) - fmaxf(ax1, cbx[cl][0]) + 1.f;
      float ih = fminf(ay2, cbx[cl][3]) - fmaxf(ay1, cbx[cl][1]) + 1.f;
      float inter = fmaxf(iw, 0.f) * fmaxf(ih, 0.f);
      float d = inter - 0.7f * (aar + cbx[cl][4] - inter);
      bool sup;
      if (d > 4.0f) sup = true;
      else if (d < -4.0f) sup = false;
      else sup = iou_gt(sbx + (size_t)r * 4, sbx + (size_t)j * 4);  // rare
      if (sup) bits |= 1ull << jj;
    }
  }
  Sup[(size_t)r * SUP_W + w] = bits;
}

// ---------------- bit-parallel greedy NMS scan ----------------
__global__ __launch_bounds__(256) void k_scan(const uint64_t* __restrict__ Sup,
                                              const double* __restrict__ ss,
                                              const double* __restrict__ sbx,
                                              float* __restrict__ out) {
  __shared__ uint16_t keep[POST_NMS];
  __shared__ uint64_t wpart[4];
  __shared__ uint64_t s_ext;
  __shared__ int kcnt;
  int t = threadIdx.x, wv = t >> 6, ln = t & 63;
  if (t == 0) kcnt = 0;
  __syncthreads();
  for (int b = 0; b < NMS_BLKS; ++b) {
    int base = b * 64;
    int K = kcnt;
    // OR of kept rows' word b  (K gathered u64 loads, spread over 256 threads)
    uint64_t m = 0ull;
    for (int p = t; p < K; p += 256) m |= Sup[(size_t)keep[p] * SUP_W + b];
#pragma unroll
    for (int off = 32; off > 0; off >>= 1) m |= __shfl_down(m, off);
    if (ln == 0) wpart[wv] = m;
    __syncthreads();
    if (t == 0) s_ext = wpart[0] | wpart[1] | wpart[2] | wpart[3];
    __syncthreads();
    if (wv == 0) {   // wave 0: ffs-driven serial scan (iterates kept only)
      uint64_t myrow = Sup[(size_t)(base + ln) * SUP_W + b] & ~((2ull << ln) - 1ull);
      uint64_t ext = s_ext;
      if (base + 63 >= PRE_NMS) {
        int v = PRE_NMS - base;                  // 48 for the tail block
        ext |= ~((1ull << v) - 1ull);
      }
      uint64_t avail = ~ext;
      uint64_t kp = 0ull;
      int K0 = kcnt, lim = POST_NMS - K0, nk = 0;
      while (avail && nk < lim) {
        int i2 = __ffsll((unsigned long long)avail) - 1;
        kp |= 1ull << i2;
        ++nk;
        uint64_t row = __shfl(myrow, i2);
        avail &= ~row;
        avail &= ~(1ull << i2);
      }
      if ((kp >> ln) & 1ull) {
        int pos = K0 + __popcll(kp & ((1ull << ln) - 1ull));
        keep[pos] = (uint16_t)(base + ln);
      }
      if (ln == 0) kcnt = K0 + nk;
    }
    __syncthreads();
    if (kcnt >= POST_NMS) break;
  }
  __syncthreads();
  int KF = kcnt;
  for (int r = t; r < POST_NMS; r += 256) {
    float* o = out + r * 6;
    if (r < KF) {
      int p = keep[r];
      o[0] = 0.f;
      o[1] = (float)sbx[p * 4 + 0];
      o[2] = (float)sbx[p * 4 + 1];
      o[3] = (float)sbx[p * 4 + 2];
      o[4] = (float)sbx[p * 4 + 3];
      o[5] = (float)ss[p];
    } else {
#pragma unroll
      for (int c = 0; c < 6; ++c) o[c] = 0.f;
    }
  }
}

// ---------------- host launch ----------------
extern "C" void kernel_launch(void* const* d_in, const int* in_sizes, int n_in,
                              void* d_out, int out_size, void* d_ws, size_t ws_size,
                              hipStream_t stream) {
  const float* p0 = (const float*)d_in[0];
  const float* p1 = (const float*)d_in[1];
  const float* p2 = (const float*)d_in[2];
  const float* p3 = (const float*)d_in[3];
  const float* p4 = (const float*)d_in[4];
  const float* im_info = (const float*)d_in[5];
  const float* cw = (const float*)d_in[6];
  const float* cb = (const float*)d_in[7];
  const float* sw = (const float*)d_in[8];
  const float* sb = (const float*)d_in[9];
  const float* bw = (const float*)d_in[10];
  const float* bb = (const float*)d_in[11];
  char* ws = (char*)d_ws;
  // ws layout (bytes):
  uint32_t* hist    = (uint32_t*)(ws + 0);         // 65536 u32 -> 262144
  uint32_t* cnts    = (uint32_t*)(ws + 262144);    // [0]=pool [1]=edge -> 262208
  double*   fb      = (double*)  (ws + 262208);    // 16 f64 -> 262336
  float*    fb32    = (float*)   (ws + 262336);    // 4 f32  -> 262352
  double*   logits  = (double*)  (ws + 262352);    // 106392 f64 -> 1113488
  double*   deltas  = (double*)  (ws + 1113488);   // 425568 f64 -> 4518032
  float*    logits32= (float*)   (ws + 4518032);   // 106392 f32 -> 4943600
  float4*   w3      = (float4*)  (ws + 4943600);   // 2304 float4 -> 4980464
  double*   Weff    = (double*)  (ws + 4980464);   // 2304*16 f64 -> 5275376
  double*   Wpart   = (double*)  (ws + 5275376);   // 16*2304*16 f64 -> 9993968
  uint32_t* alist   = (uint32_t*)(ws + 9993968);   // 8192 u32 -> 10026736
  double*   ssort   = (double*)  (ws + 10026736);  // 6016 f64 -> 10074864
  double*   sbx     = (double*)  (ws + 10074864);  // 6016*4 f64 -> 10267376
  float4*   bxf     = (float4*)  (ws + 10267376);  // 6016 float4 -> 10363632
  float*    areaf   = (float*)   (ws + 10363632);  // 6016 f32 -> 10387696
  uint64_t* Sup     = (uint64_t*)(ws + 10387696);  // 6016*96 u64 -> 15007984
  float* out = (float*)d_out;

  hipMemsetAsync(ws, 0, 262208, stream);           // hist + counters
  k_weff_part<<<144, 256, 0, stream>>>(cw, sw, bw, Wpart);
  k_weff_fin<<<10, 256, 0, stream>>>(Wpart, cb, sb, bb, sw, bw, Weff, fb, w3, fb32);
  k_fast<<<555, 256, 0, stream>>>(p0, p1, p2, p3, p4, w3, fb32, logits32, hist);
  k_edge<<<1, 1024, 0, stream>>>(hist, cnts);
  k_compact<<<416, 256, 0, stream>>>(logits32, cnts, alist);
  k_refine<<<128, 256, 0, stream>>>(p0, p1, p2, p3, p4, Weff, fb, alist, cnts,
                                    logits, deltas);
  k_sort<<<1, 1024, 0, stream>>>(cnts, alist, logits, deltas, im_info, ssort, sbx,
                                 bxf, areaf);
  k_build<<<94 * 24, 256, 0, stream>>>(sbx, bxf, areaf, Sup);
  k_scan<<<1, 256, 0, stream>>>(Sup, ssort, sbx, out);
}

// Round 7
// 600.929 us; speedup vs baseline: 36.9942x; 1.0735x over previous
//
#include <hip/hip_runtime.h>
#include <stdint.h>

#define N_ANCH   106392
#define PRE_NMS  6000
#define POST_NMS 1000
#define POOL_CAP 8192
#define NMS_BLKS 94   // 94*64 = 6016 >= 6000
#define SUP_W    96   // padded words per suppression row

static __device__ const int    LV_H[5]      = {128, 64, 32, 16, 8};
static __device__ const int    LV_W[5]      = {208, 104, 52, 26, 13};
static __device__ const int    LV_STRIDE[5] = {4, 8, 16, 32, 64};
static __device__ const int    LV_PIX[5]    = {26624, 6656, 1664, 416, 104};
static __device__ const int    LV_TILE0[6]  = {0, 416, 520, 546, 553, 555};
static __device__ const int    LV_AOFF[6]   = {0, 79872, 99840, 104832, 106080, 106392};
static __device__ const int    GPOFF[6]     = {0, 26624, 33280, 34944, 35360, 35464};
// Base anchors computed with np.round (half-even) semantics, verified by hand.
static __device__ const double BASE_ANCH[5][3][4] = {
  {{-22.,-10.,25.,13.},   {-14.,-14.,17.,17.},    {-10.,-22.,13.,25.}},
  {{-40.,-20.,47.,27.},   {-28.,-28.,35.,35.},    {-20.,-44.,27.,51.}},
  {{-84.,-40.,99.,55.},   {-56.,-56.,71.,71.},    {-36.,-80.,51.,95.}},
  {{-164.,-72.,195.,103.},{-112.,-112.,143.,143.},{-76.,-168.,107.,199.}},
  {{-332.,-152.,395.,215.},{-224.,-224.,287.,287.},{-148.,-328.,211.,391.}}
};

// sortable mappings (monotone): bigger value -> bigger key
__device__ __forceinline__ uint32_t sort32f(float f) {
  uint32_t u = __float_as_uint(f);
  return ((int)u < 0) ? ~u : (u | 0x80000000u);
}
__device__ __forceinline__ uint64_t sort64(double d) {
  uint64_t u = (uint64_t)__double_as_longlong(d);
  return ((long long)u < 0) ? ~u : (u | 0x8000000000000000ull);
}

// ---------------- f64 effective weights, 2-stage ----------------
// comb inline: j<3 -> sw[3+j][c]-sw[j][c]; 3<=j<15 -> bw[j-3][c]
__device__ __forceinline__ double combf(const float* sw, const float* bw, int c, int j) {
  if (j < 3) return (double)sw[(3 + j) * 512 + c] - (double)sw[j * 512 + c];
  return (double)bw[(j - 3) * 512 + c];
}

__global__ __launch_bounds__(256) void k_weff_part(const float* __restrict__ cw,
                                                   const float* __restrict__ sw,
                                                   const float* __restrict__ bw,
                                                   double* __restrict__ Wpart) {
  int chunk = blockIdx.x / 9;            // 16 chunks of 32 channels
  int tb = blockIdx.x % 9;               // 9 t-blocks of 256
  int t = tb * 256 + threadIdx.x;        // 0..2303
  int c0 = chunk * 32;
  double acc[15];
#pragma unroll
  for (int j = 0; j < 15; ++j) acc[j] = 0.0;
#pragma unroll 1
  for (int c = c0; c < c0 + 32; ++c) {
    double v = (double)cw[c * 2304 + t];
#pragma unroll
    for (int j = 0; j < 15; ++j) acc[j] += v * combf(sw, bw, c, j);
  }
  double* o = Wpart + (((size_t)chunk * 2304 + t) << 4);
#pragma unroll
  for (int j = 0; j < 15; ++j) o[j] = acc[j];
  o[15] = 0.0;
}

// blocks 0..8: Weff[t][j] = sum over chunks; also emit f32 screen weights w3.
// block 9: fb f64 + fb32.
__global__ __launch_bounds__(256) void k_weff_fin(const double* __restrict__ Wpart,
                                                  const float* __restrict__ cb,
                                                  const float* __restrict__ sb,
                                                  const float* __restrict__ bb,
                                                  const float* __restrict__ sw,
                                                  const float* __restrict__ bw,
                                                  double* __restrict__ Weff,
                                                  double* __restrict__ fb,
                                                  float4* __restrict__ w3,
                                                  float* __restrict__ fb32) {
  if (blockIdx.x == 9) {
    __shared__ double ps[15][16];
    int tid = threadIdx.x;
    if (tid < 240) {
      int j = tid >> 4, part = tid & 15;
      double s = 0.0;
      for (int c = part * 32; c < part * 32 + 32; ++c)
        s += (double)cb[c] * combf(sw, bw, c, j);
      ps[j][part] = s;
    }
    __syncthreads();
    if (tid < 15) {
      double s = 0.0;
#pragma unroll
      for (int part = 0; part < 16; ++part) s += ps[tid][part];  // fixed order
      s += (tid < 3) ? ((double)sb[3 + tid] - (double)sb[tid]) : (double)bb[tid - 3];
      fb[tid] = s;
      if (tid < 3) fb32[tid] = (float)s;
    }
    if (tid == 15) fb32[3] = 0.f;
    return;
  }
  int t = blockIdx.x * 256 + threadIdx.x;
  double acc[15];
#pragma unroll
  for (int j = 0; j < 15; ++j) acc[j] = 0.0;
#pragma unroll 1
  for (int chunk = 0; chunk < 16; ++chunk) {
    const double* p = Wpart + (((size_t)chunk * 2304 + t) << 4);
#pragma unroll
    for (int j = 0; j < 15; ++j) acc[j] += p[j];
  }
  double* o = Weff + ((size_t)t << 4);
#pragma unroll
  for (int j = 0; j < 15; ++j) o[j] = acc[j];
  o[15] = 0.0;
  float4 wf;
  wf.x = (float)acc[0]; wf.y = (float)acc[1]; wf.z = (float)acc[2]; wf.w = 0.f;
  w3[t] = wf;
}

// ---------------- f32 screening pass: 3 logits/pixel + histogram ----------------
__device__ __forceinline__ void load9(float v[9], const float* __restrict__ ib,
                                      const bool rok[3], const bool cok[3],
                                      const int roff[3]) {
#pragma unroll
  for (int ky = 0; ky < 3; ++ky)
#pragma unroll
    for (int kx = 0; kx < 3; ++kx)
      v[ky * 3 + kx] = (rok[ky] && cok[kx]) ? ib[roff[ky] + kx] : 0.0f;
}

__global__ __launch_bounds__(256) void k_fast(
    const float* __restrict__ p0, const float* __restrict__ p1,
    const float* __restrict__ p2, const float* __restrict__ p3,
    const float* __restrict__ p4,
    const float4* __restrict__ w3, const float* __restrict__ fb32,
    float* __restrict__ logits32, uint32_t* __restrict__ hist) {
  __shared__ float4 w3s[2304];       // 36.9 KB, LDS-resident weights
  __shared__ float red[4][64][3];
  int tid = threadIdx.x, wv = tid >> 6, ln = tid & 63;
  for (int i = tid; i < 2304; i += 256) w3s[i] = w3[i];
  int t = blockIdx.x;
  int L = 0;
  while (L < 4 && t >= LV_TILE0[L + 1]) ++L;
  const float* inL = (L == 0) ? p0 : (L == 1) ? p1 : (L == 2) ? p2 : (L == 3) ? p3 : p4;
  int H = LV_H[L], W = LV_W[L], HW = H * W, PIX = LV_PIX[L];
  int pix = (t - LV_TILE0[L]) * 64 + ln;
  bool valid = pix < PIX;
  if (!valid) pix = PIX - 1;
  int h = pix / W, w = pix % W;
  bool rok[3], cok[3];
  int roff[3];
#pragma unroll
  for (int ky = 0; ky < 3; ++ky) {
    int iy = h + ky - 1;
    rok[ky] = (iy >= 0 && iy < H);
    roff[ky] = iy * W + w - 1;
  }
#pragma unroll
  for (int kx = 0; kx < 3; ++kx) {
    int ix = w + kx - 1;
    cok[kx] = (ix >= 0 && ix < W);
  }
  __syncthreads();
  float a0 = 0.f, a1 = 0.f, a2 = 0.f;
  int ci0 = wv * 64;
  const float* ib = inL + ci0 * HW;
#pragma unroll 1
  for (int ci = ci0; ci < ci0 + 64; ++ci, ib += HW) {
    float v[9];
    load9(v, ib, rok, cok, roff);
    const float4* wr = w3s + ci * 9;
#pragma unroll
    for (int t9 = 0; t9 < 9; ++t9) {
      float4 wt = wr[t9];                  // broadcast ds_read_b128
      float vv = v[t9];
      a0 += vv * wt.x; a1 += vv * wt.y; a2 += vv * wt.z;
    }
  }
  red[wv][ln][0] = a0; red[wv][ln][1] = a1; red[wv][ln][2] = a2;
  __syncthreads();
  if (wv == 0 && valid) {
    int gbase = LV_AOFF[L] + pix * 3;
#pragma unroll
    for (int a = 0; a < 3; ++a) {
      float f = (red[0][ln][a] + red[1][ln][a]) + (red[2][ln][a] + red[3][ln][a]);
      f += fb32[a];
      logits32[gbase + a] = f;
      atomicAdd(&hist[sort32f(f) >> 16], 1u);
    }
  }
}

// ---------------- edge finder (with 2-bin safety margin) ----------------
__global__ __launch_bounds__(1024) void k_edge(const uint32_t* __restrict__ hist,
                                               uint32_t* __restrict__ cnts) {
  __shared__ uint32_t cs[1024];
  __shared__ uint32_t g_grp, g_suf;
  int t = threadIdx.x, wv = t >> 6, ln = t & 63;
#pragma unroll 4
  for (int r = 0; r < 64; ++r) {
    int g = r * 16 + wv;
    uint32_t x = hist[g * 64 + ln];
#pragma unroll
    for (int off = 32; off > 0; off >>= 1) x += __shfl_down(x, off);
    if (ln == 0) cs[g] = x;
  }
  __syncthreads();
  for (int off = 1; off < 1024; off <<= 1) {
    uint32_t v = cs[t] + ((t + off < 1024) ? cs[t + off] : 0u);
    __syncthreads();
    cs[t] = v;
    __syncthreads();
  }
  uint32_t sufnext = (t < 1023) ? cs[t + 1] : 0u;
  if (cs[t] >= PRE_NMS && sufnext < PRE_NMS) {   // unique t
    g_grp = (uint32_t)t;
    g_suf = sufnext;
  }
  __syncthreads();
  if (t < 64) {   // wave 0: refine edge within the winning 64-bin group
    uint32_t grp = g_grp, suf = g_suf;
    uint32_t x = hist[grp * 64 + t];
    uint32_t S = x;
#pragma unroll
    for (int off = 1; off < 64; off <<= 1) {
      uint32_t y = __shfl_down(S, off);
      if (t + off < 64) S += y;
    }
    unsigned long long mask = __ballot(suf + S >= PRE_NMS);
    int hi = 63 - (int)__clzll(mask);
    if (t == hi) {
      uint32_t e = grp * 64 + (uint32_t)hi;
      cnts[1] = (e > 2) ? e - 2 : 0;     // -2 bin margin: f32 superset of f64 top-k
    }
  }
}

// ---------------- pool compaction (f32 screen) ----------------
__global__ __launch_bounds__(256) void k_compact(const float* __restrict__ logits32,
                                                 uint32_t* __restrict__ cnts,
                                                 uint32_t* __restrict__ alist) {
  int i = blockIdx.x * 256 + threadIdx.x;
  if (i >= N_ANCH) return;
  if ((sort32f(logits32[i]) >> 16) >= cnts[1]) {
    uint32_t pos = atomicAdd(&cnts[0], 1u);
    if (pos < POOL_CAP) alist[pos] = (uint32_t)i;
  }
}

// ---------------- f64 refine: exact logit + deltas + sort key ----------------
__global__ __launch_bounds__(256) void k_refine(
    const float* __restrict__ p0, const float* __restrict__ p1,
    const float* __restrict__ p2, const float* __restrict__ p3,
    const float* __restrict__ p4,
    const double* __restrict__ Weff, const double* __restrict__ fb,
    const uint32_t* __restrict__ alist, const uint32_t* __restrict__ cnts,
    double* __restrict__ logits, double* __restrict__ deltas,
    uint64_t* __restrict__ pkey) {
  __shared__ double red[4][64][5];
  int tid = threadIdx.x, wv = tid >> 6, ln = tid & 63;
  int cnt = (int)cnts[0];
  if (cnt > POOL_CAP) cnt = POOL_CAP;
  int base = blockIdx.x * 64;
  if (base >= cnt) return;                 // uniform early-exit
  int slot = base + ln;
  if (slot >= cnt) slot = cnt - 1;         // dup tail (benign same-value writes)
  int gi = (int)alist[slot];
  int gpix = gi / 3, a = gi - gpix * 3;
  int L = 0;
  while (L < 4 && gpix >= GPOFF[L + 1]) ++L;
  int pix = gpix - GPOFF[L];
  const float* inL = (L == 0) ? p0 : (L == 1) ? p1 : (L == 2) ? p2 : (L == 3) ? p3 : p4;
  int H = LV_H[L], W = LV_W[L], HW = H * W;
  int h = pix / W, w = pix % W;
  bool rok[3], cok[3];
  int roff[3];
#pragma unroll
  for (int ky = 0; ky < 3; ++ky) {
    int iy = h + ky - 1;
    rok[ky] = (iy >= 0 && iy < H);
    roff[ky] = iy * W + w - 1;
  }
#pragma unroll
  for (int kx = 0; kx < 3; ++kx) {
    int ix = w + kx - 1;
    cok[kx] = (ix >= 0 && ix < W);
  }
  double sc = 0.0, d0 = 0.0, d1 = 0.0, d2 = 0.0, d3 = 0.0;
  int js = a, jd = 3 + 4 * a;
  int ci0 = wv * 64;
  const float* ib = inL + ci0 * HW;
#pragma unroll 1
  for (int ci = ci0; ci < ci0 + 64; ++ci, ib += HW) {
    float v[9];
    load9(v, ib, rok, cok, roff);
    const double* wr = Weff + ((size_t)ci * 144);
#pragma unroll
    for (int t9 = 0; t9 < 9; ++t9) {
      double vd = (double)v[t9];
      const double* wt = wr + t9 * 16;
      sc += vd * wt[js];
      d0 += vd * wt[jd + 0];
      d1 += vd * wt[jd + 1];
      d2 += vd * wt[jd + 2];
      d3 += vd * wt[jd + 3];
    }
  }
  red[wv][ln][0] = sc;
  red[wv][ln][1] = d0; red[wv][ln][2] = d1;
  red[wv][ln][3] = d2; red[wv][ln][4] = d3;
  __syncthreads();
  if (wv == 0) {
    double f[5];
#pragma unroll
    for (int j = 0; j < 5; ++j)
      f[j] = red[0][ln][j] + red[1][ln][j] + red[2][ln][j] + red[3][ln][j];
    double lg = f[0] + fb[js];
    logits[gi] = lg;
    deltas[gi * 4 + 0] = f[1] + fb[jd + 0];
    deltas[gi * 4 + 1] = f[2] + fb[jd + 1];
    deltas[gi * 4 + 2] = f[3] + fb[jd + 2];
    deltas[gi * 4 + 3] = f[4] + fb[jd + 3];
    // top-47 bits of sortable f64 logit; low 17 bits inverted index ->
    // rank-descending breaks score ties by ascending index (top_k semantics)
    pkey[slot] = (sort64(lg) & ~0x1FFFFull) | (uint64_t)(0x1FFFFu - (uint32_t)gi);
  }
}

// ---------------- rank-by-counting (keys unique) + scatter + box decode ----------------
__global__ __launch_bounds__(256) void k_rank(const uint32_t* __restrict__ cnts,
                                              const uint64_t* __restrict__ pkey,
                                              const double* __restrict__ logits,
                                              const double* __restrict__ deltas,
                                              const float* __restrict__ im_info,
                                              double* __restrict__ ss,
                                              double* __restrict__ sbx,
                                              float4* __restrict__ bxf,
                                              float* __restrict__ areaf) {
  __shared__ uint64_t lk[2048];
  int t = threadIdx.x;
  int cnt = (int)cnts[0];
  if (cnt > POOL_CAP) cnt = POOL_CAP;
  int e = blockIdx.x * 256 + t;
  if (blockIdx.x * 256 >= cnt) return;     // uniform
  bool active = e < cnt;
  uint64_t mykey = active ? pkey[e] : 0ull;
  int rank = 0;
  for (int c0 = 0; c0 < cnt; c0 += 2048) {
    int lim = cnt - c0; if (lim > 2048) lim = 2048;
    __syncthreads();
    for (int i = t; i < lim; i += 256) lk[i] = pkey[c0 + i];
    __syncthreads();
    if (active) {
#pragma unroll 4
      for (int j = 0; j < lim; ++j) rank += (lk[j] > mykey) ? 1 : 0;
    }
  }
  if (!active || rank >= PRE_NMS) return;
  int gi = 0x1FFFF - (int)(mykey & 0x1FFFFull);
  int L = 0;
  while (L < 4 && gi >= LV_AOFF[L + 1]) ++L;
  int rel = gi - LV_AOFF[L];
  int pix = rel / 3, a = rel % 3;
  int W = LV_W[L];
  int h = pix / W, w = pix % W;
  double imW1 = (double)im_info[1] - 1.0;
  double imH1 = (double)im_info[0] - 1.0;
  double shx = (double)(w * LV_STRIDE[L]), shy = (double)(h * LV_STRIDE[L]);
  double ax1 = BASE_ANCH[L][a][0] + shx, ay1 = BASE_ANCH[L][a][1] + shy;
  double ax2 = BASE_ANCH[L][a][2] + shx, ay2 = BASE_ANCH[L][a][3] + shy;
  double dx = deltas[gi * 4 + 0], dy = deltas[gi * 4 + 1];
  double dw = deltas[gi * 4 + 2], dh = deltas[gi * 4 + 3];
  double wa = ax2 - ax1 + 1.0, ha = ay2 - ay1 + 1.0;
  double cx = ax1 + 0.5 * wa, cy = ay1 + 0.5 * ha;
  double pcx = dx * wa + cx, pcy = dy * ha + cy;
  double pw = exp(dw) * wa, ph = exp(dh) * ha;
  double x1 = fmin(fmax(pcx - 0.5 * pw, 0.0), imW1);
  double y1 = fmin(fmax(pcy - 0.5 * ph, 0.0), imH1);
  double x2 = fmin(fmax(pcx + 0.5 * pw, 0.0), imW1);
  double y2 = fmin(fmax(pcy + 0.5 * ph, 0.0), imH1);
  ss[rank] = 1.0 / (1.0 + exp(-logits[gi]));
  sbx[rank * 4 + 0] = x1; sbx[rank * 4 + 1] = y1;
  sbx[rank * 4 + 2] = x2; sbx[rank * 4 + 3] = y2;
  float4 bf;
  bf.x = (float)x1; bf.y = (float)y1; bf.z = (float)x2; bf.w = (float)y2;
  bxf[rank] = bf;
  areaf[rank] = (float)((x2 - x1 + 1.0) * (y2 - y1 + 1.0));
}

// ---------------- exact f64 IoU decision (reference semantics) ----------------
__device__ __forceinline__ bool iou_gt(const double* A, const double* B) {
  double areaA = (A[2] - A[0] + 1.0) * (A[3] - A[1] + 1.0);
  double areaB = (B[2] - B[0] + 1.0) * (B[3] - B[1] + 1.0);
  double xx1 = fmax(A[0], B[0]), yy1 = fmax(A[1], B[1]);
  double xx2 = fmin(A[2], B[2]), yy2 = fmin(A[3], B[3]);
  double iw = fmax(0.0, xx2 - xx1 + 1.0), ih = fmax(0.0, yy2 - yy1 + 1.0);
  double inter = iw * ih;
  return inter > 0.7 * (areaA + areaB - inter);
}

// ---------------- suppression matrix build (upper triangle) ----------------
// Sup[r][w] bit jj set  <=>  IoU(box r, box w*64+jj) > 0.7, for j > r.
// f32 prefilter with +-4.0 absolute margin on (inter - 0.7*union); f64 confirm
// in the gray zone -> decisions identical to pure f64. Rows/cols >= PRE_NMS
// may read unwritten (poisoned) staging rows; their bits are masked in k_scan.
__global__ __launch_bounds__(256) void k_build(const double* __restrict__ sbx,
                                               const float4* __restrict__ bxf,
                                               const float* __restrict__ areaf,
                                               uint64_t* __restrict__ Sup) {
  __shared__ float cbx[256][5];
  __shared__ float rbx[64][5];
  int blk = blockIdx.x;
  int rtile = blk / 24, ctile = blk % 24;   // 94 x 24
  int t = threadIdx.x, q = t >> 6, ln = t & 63;
  int r = rtile * 64 + ln;
  int w = ctile * 4 + q;                    // word 0..95
  {
    int c = ctile * 256 + t;
    float4 b;
    float ar;
    if (c < NMS_BLKS * 64) { b = bxf[c]; ar = areaf[c]; }
    else { b.x = b.y = b.z = b.w = 0.f; ar = 0.f; }
    cbx[t][0] = b.x; cbx[t][1] = b.y; cbx[t][2] = b.z; cbx[t][3] = b.w; cbx[t][4] = ar;
    if (t < 64) {
      int rr = rtile * 64 + t;
      float4 rb = bxf[rr];
      rbx[t][0] = rb.x; rbx[t][1] = rb.y; rbx[t][2] = rb.z; rbx[t][3] = rb.w;
      rbx[t][4] = areaf[rr];
    }
  }
  __syncthreads();
  uint64_t bits = 0ull;
  int j0 = w * 64;
  if (w < NMS_BLKS && j0 + 63 > r) {
    float ax1 = rbx[ln][0], ay1 = rbx[ln][1], ax2 = rbx[ln][2], ay2 = rbx[ln][3];
    float aar = rbx[ln][4];
#pragma unroll 4
    for (int jj = 0; jj < 64; ++jj) {
      int j = j0 + jj;
      if (j <= r) continue;
      int cl = q * 64 + jj;
      float iw = fminf(ax2, cbx[cl][2]) - fmaxf(ax1, cbx[cl][0]) + 1.f;
      float ih = fminf(ay2, cbx[cl][3]) - fmaxf(ay1, cbx[cl][1]) + 1.f;
      float inter = fmaxf(iw, 0.f) * fmaxf(ih, 0.f);
      float d = inter - 0.7f * (aar + cbx[cl][4] - inter);
      bool sup;
      if (d > 4.0f) sup = true;
      else if (d < -4.0f) sup = false;
      else sup = iou_gt(sbx + (size_t)r * 4, sbx + (size_t)j * 4);  // rare
      if (sup) bits |= 1ull << jj;
    }
  }
  Sup[(size_t)r * SUP_W + w] = bits;
}

// ---------------- bit-parallel greedy NMS scan ----------------
__global__ __launch_bounds__(256) void k_scan(const uint64_t* __restrict__ Sup,
                                              const double* __restrict__ ss,
                                              const double* __restrict__ sbx,
                                              float* __restrict__ out) {
  __shared__ uint16_t keep[POST_NMS];
  __shared__ uint64_t wpart[4];
  __shared__ uint64_t s_ext;
  __shared__ int kcnt;
  int t = threadIdx.x, wv = t >> 6, ln = t & 63;
  if (t == 0) kcnt = 0;
  __syncthreads();
  for (int b = 0; b < NMS_BLKS; ++b) {
    int base = b * 64;
    int K = kcnt;
    // OR of kept rows' word b  (K gathered u64 loads, spread over 256 threads)
    uint64_t m = 0ull;
    for (int p = t; p < K; p += 256) m |= Sup[(size_t)keep[p] * SUP_W + b];
#pragma unroll
    for (int off = 32; off > 0; off >>= 1) m |= __shfl_down(m, off);
    if (ln == 0) wpart[wv] = m;
    __syncthreads();
    if (t == 0) s_ext = wpart[0] | wpart[1] | wpart[2] | wpart[3];
    __syncthreads();
    if (wv == 0) {   // wave 0: ffs-driven serial scan (iterates kept only)
      uint64_t myrow = Sup[(size_t)(base + ln) * SUP_W + b] & ~((2ull << ln) - 1ull);
      uint64_t ext = s_ext;
      if (base + 63 >= PRE_NMS) {
        int v = PRE_NMS - base;                  // 48 for the tail block
        ext |= ~((1ull << v) - 1ull);
      }
      uint64_t avail = ~ext;
      uint64_t kp = 0ull;
      int K0 = kcnt, lim = POST_NMS - K0, nk = 0;
      while (avail && nk < lim) {
        int i2 = __ffsll((unsigned long long)avail) - 1;
        kp |= 1ull << i2;
        ++nk;
        uint64_t row = __shfl(myrow, i2);
        avail &= ~row;
        avail &= ~(1ull << i2);
      }
      if ((kp >> ln) & 1ull) {
        int pos = K0 + __popcll(kp & ((1ull << ln) - 1ull));
        keep[pos] = (uint16_t)(base + ln);
      }
      if (ln == 0) kcnt = K0 + nk;
    }
    __syncthreads();
    if (kcnt >= POST_NMS) break;
  }
  __syncthreads();
  int KF = kcnt;
  for (int r = t; r < POST_NMS; r += 256) {
    float* o = out + r * 6;
    if (r < KF) {
      int p = keep[r];
      o[0] = 0.f;
      o[1] = (float)sbx[p * 4 + 0];
      o[2] = (float)sbx[p * 4 + 1];
      o[3] = (float)sbx[p * 4 + 2];
      o[4] = (float)sbx[p * 4 + 3];
      o[5] = (float)ss[p];
    } else {
#pragma unroll
      for (int c = 0; c < 6; ++c) o[c] = 0.f;
    }
  }
}

// ---------------- host launch ----------------
extern "C" void kernel_launch(void* const* d_in, const int* in_sizes, int n_in,
                              void* d_out, int out_size, void* d_ws, size_t ws_size,
                              hipStream_t stream) {
  const float* p0 = (const float*)d_in[0];
  const float* p1 = (const float*)d_in[1];
  const float* p2 = (const float*)d_in[2];
  const float* p3 = (const float*)d_in[3];
  const float* p4 = (const float*)d_in[4];
  const float* im_info = (const float*)d_in[5];
  const float* cw = (const float*)d_in[6];
  const float* cb = (const float*)d_in[7];
  const float* sw = (const float*)d_in[8];
  const float* sb = (const float*)d_in[9];
  const float* bw = (const float*)d_in[10];
  const float* bb = (const float*)d_in[11];
  char* ws = (char*)d_ws;
  // ws layout (bytes):
  uint32_t* hist    = (uint32_t*)(ws + 0);         // 65536 u32 -> 262144
  uint32_t* cnts    = (uint32_t*)(ws + 262144);    // [0]=pool [1]=edge -> 262208
  double*   fb      = (double*)  (ws + 262208);    // 16 f64 -> 262336
  float*    fb32    = (float*)   (ws + 262336);    // 4 f32  -> 262352
  double*   logits  = (double*)  (ws + 262352);    // 106392 f64 -> 1113488
  double*   deltas  = (double*)  (ws + 1113488);   // 425568 f64 -> 4518032
  float*    logits32= (float*)   (ws + 4518032);   // 106392 f32 -> 4943600
  float4*   w3      = (float4*)  (ws + 4943600);   // 2304 float4 -> 4980464
  double*   Weff    = (double*)  (ws + 4980464);   // 2304*16 f64 -> 5275376
  double*   Wpart   = (double*)  (ws + 5275376);   // 16*2304*16 f64 -> 9993968
  uint32_t* alist   = (uint32_t*)(ws + 9993968);   // 8192 u32 -> 10026736
  double*   ssort   = (double*)  (ws + 10026736);  // 6016 f64 -> 10074864
  double*   sbx     = (double*)  (ws + 10074864);  // 6016*4 f64 -> 10267376
  float4*   bxf     = (float4*)  (ws + 10267376);  // 6016 float4 -> 10363632
  float*    areaf   = (float*)   (ws + 10363632);  // 6016 f32 -> 10387696
  uint64_t* Sup     = (uint64_t*)(ws + 10387696);  // 6016*96 u64 -> 15007984
  uint64_t* pkey    = (uint64_t*)(ws + 15007984);  // 8192 u64 -> 15073520
  float* out = (float*)d_out;

  hipMemsetAsync(ws, 0, 262208, stream);           // hist + counters
  k_weff_part<<<144, 256, 0, stream>>>(cw, sw, bw, Wpart);
  k_weff_fin<<<10, 256, 0, stream>>>(Wpart, cb, sb, bb, sw, bw, Weff, fb, w3, fb32);
  k_fast<<<555, 256, 0, stream>>>(p0, p1, p2, p3, p4, w3, fb32, logits32, hist);
  k_edge<<<1, 1024, 0, stream>>>(hist, cnts);
  k_compact<<<416, 256, 0, stream>>>(logits32, cnts, alist);
  k_refine<<<128, 256, 0, stream>>>(p0, p1, p2, p3, p4, Weff, fb, alist, cnts,
                                    logits, deltas, pkey);
  k_rank<<<32, 256, 0, stream>>>(cnts, pkey, logits, deltas, im_info,
                                 ssort, sbx, bxf, areaf);
  k_build<<<94 * 24, 256, 0, stream>>>(sbx, bxf, areaf, Sup);
  k_scan<<<1, 256, 0, stream>>>(Sup, ssort, sbx, out);
}

// Round 8
// 500.716 us; speedup vs baseline: 44.3981x; 1.2001x over previous
//
#include <hip/hip_runtime.h>
#include <stdint.h>

#define N_ANCH   106392
#define PRE_NMS  6000
#define POST_NMS 1000
#define POOL_CAP 8192
#define NMS_BLKS 94   // 94*64 = 6016 >= 6000
#define SUP_W    96   // padded words per suppression row

static __device__ const int    LV_H[5]      = {128, 64, 32, 16, 8};
static __device__ const int    LV_W[5]      = {208, 104, 52, 26, 13};
static __device__ const int    LV_STRIDE[5] = {4, 8, 16, 32, 64};
static __device__ const int    LV_PIX[5]    = {26624, 6656, 1664, 416, 104};
static __device__ const int    LV_TILE0[6]  = {0, 416, 520, 546, 553, 555};
static __device__ const int    LV_AOFF[6]   = {0, 79872, 99840, 104832, 106080, 106392};
static __device__ const int    GPOFF[6]     = {0, 26624, 33280, 34944, 35360, 35464};
// Base anchors computed with np.round (half-even) semantics, verified by hand.
static __device__ const double BASE_ANCH[5][3][4] = {
  {{-22.,-10.,25.,13.},   {-14.,-14.,17.,17.},    {-10.,-22.,13.,25.}},
  {{-40.,-20.,47.,27.},   {-28.,-28.,35.,35.},    {-20.,-44.,27.,51.}},
  {{-84.,-40.,99.,55.},   {-56.,-56.,71.,71.},    {-36.,-80.,51.,95.}},
  {{-164.,-72.,195.,103.},{-112.,-112.,143.,143.},{-76.,-168.,107.,199.}},
  {{-332.,-152.,395.,215.},{-224.,-224.,287.,287.},{-148.,-328.,211.,391.}}
};

// sortable mappings (monotone): bigger value -> bigger key
__device__ __forceinline__ uint32_t sort32f(float f) {
  uint32_t u = __float_as_uint(f);
  return ((int)u < 0) ? ~u : (u | 0x80000000u);
}
__device__ __forceinline__ uint64_t sort64(double d) {
  uint64_t u = (uint64_t)__double_as_longlong(d);
  return ((long long)u < 0) ? ~u : (u | 0x8000000000000000ull);
}

// ---------------- f64 effective weights, 2-stage ----------------
// comb inline: j<3 -> sw[3+j][c]-sw[j][c]; 3<=j<15 -> bw[j-3][c]
__device__ __forceinline__ double combf(const float* sw, const float* bw, int c, int j) {
  if (j < 3) return (double)sw[(3 + j) * 512 + c] - (double)sw[j * 512 + c];
  return (double)bw[(j - 3) * 512 + c];
}

__global__ __launch_bounds__(256) void k_weff_part(const float* __restrict__ cw,
                                                   const float* __restrict__ sw,
                                                   const float* __restrict__ bw,
                                                   double* __restrict__ Wpart) {
  int chunk = blockIdx.x / 9;            // 16 chunks of 32 channels
  int tb = blockIdx.x % 9;               // 9 t-blocks of 256
  int t = tb * 256 + threadIdx.x;        // 0..2303
  int c0 = chunk * 32;
  double acc[15];
#pragma unroll
  for (int j = 0; j < 15; ++j) acc[j] = 0.0;
#pragma unroll 1
  for (int c = c0; c < c0 + 32; ++c) {
    double v = (double)cw[c * 2304 + t];
#pragma unroll
    for (int j = 0; j < 15; ++j) acc[j] += v * combf(sw, bw, c, j);
  }
  double* o = Wpart + (((size_t)chunk * 2304 + t) << 4);
#pragma unroll
  for (int j = 0; j < 15; ++j) o[j] = acc[j];
  o[15] = 0.0;
}

// blocks 0..8: Weff[t][j] = sum over chunks; also emit f32 screen weights w3.
// block 9: fb f64 + fb32.
__global__ __launch_bounds__(256) void k_weff_fin(const double* __restrict__ Wpart,
                                                  const float* __restrict__ cb,
                                                  const float* __restrict__ sb,
                                                  const float* __restrict__ bb,
                                                  const float* __restrict__ sw,
                                                  const float* __restrict__ bw,
                                                  double* __restrict__ Weff,
                                                  double* __restrict__ fb,
                                                  float4* __restrict__ w3,
                                                  float* __restrict__ fb32) {
  if (blockIdx.x == 9) {
    __shared__ double ps[15][16];
    int tid = threadIdx.x;
    if (tid < 240) {
      int j = tid >> 4, part = tid & 15;
      double s = 0.0;
      for (int c = part * 32; c < part * 32 + 32; ++c)
        s += (double)cb[c] * combf(sw, bw, c, j);
      ps[j][part] = s;
    }
    __syncthreads();
    if (tid < 15) {
      double s = 0.0;
#pragma unroll
      for (int part = 0; part < 16; ++part) s += ps[tid][part];  // fixed order
      s += (tid < 3) ? ((double)sb[3 + tid] - (double)sb[tid]) : (double)bb[tid - 3];
      fb[tid] = s;
      if (tid < 3) fb32[tid] = (float)s;
    }
    if (tid == 15) fb32[3] = 0.f;
    return;
  }
  int t = blockIdx.x * 256 + threadIdx.x;
  double acc[15];
#pragma unroll
  for (int j = 0; j < 15; ++j) acc[j] = 0.0;
#pragma unroll 1
  for (int chunk = 0; chunk < 16; ++chunk) {
    const double* p = Wpart + (((size_t)chunk * 2304 + t) << 4);
#pragma unroll
    for (int j = 0; j < 15; ++j) acc[j] += p[j];
  }
  double* o = Weff + ((size_t)t << 4);
#pragma unroll
  for (int j = 0; j < 15; ++j) o[j] = acc[j];
  o[15] = 0.0;
  float4 wf;
  wf.x = (float)acc[0]; wf.y = (float)acc[1]; wf.z = (float)acc[2]; wf.w = 0.f;
  w3[t] = wf;
}

// ---------------- f32 screening pass: 3 logits/pixel + histogram ----------------
__device__ __forceinline__ void load9(float v[9], const float* __restrict__ ib,
                                      const bool rok[3], const bool cok[3],
                                      const int roff[3]) {
#pragma unroll
  for (int ky = 0; ky < 3; ++ky)
#pragma unroll
    for (int kx = 0; kx < 3; ++kx)
      v[ky * 3 + kx] = (rok[ky] && cok[kx]) ? ib[roff[ky] + kx] : 0.0f;
}

__global__ __launch_bounds__(256) void k_fast(
    const float* __restrict__ p0, const float* __restrict__ p1,
    const float* __restrict__ p2, const float* __restrict__ p3,
    const float* __restrict__ p4,
    const float4* __restrict__ w3, const float* __restrict__ fb32,
    float* __restrict__ logits32, uint32_t* __restrict__ hist) {
  __shared__ float4 w3s[2304];       // 36.9 KB, LDS-resident weights
  __shared__ float red[4][64][3];
  int tid = threadIdx.x, wv = tid >> 6, ln = tid & 63;
  for (int i = tid; i < 2304; i += 256) w3s[i] = w3[i];
  int t = blockIdx.x;
  int L = 0;
  while (L < 4 && t >= LV_TILE0[L + 1]) ++L;
  const float* inL = (L == 0) ? p0 : (L == 1) ? p1 : (L == 2) ? p2 : (L == 3) ? p3 : p4;
  int H = LV_H[L], W = LV_W[L], HW = H * W, PIX = LV_PIX[L];
  int pix = (t - LV_TILE0[L]) * 64 + ln;
  bool valid = pix < PIX;
  if (!valid) pix = PIX - 1;
  int h = pix / W, w = pix % W;
  bool rok[3], cok[3];
  int roff[3];
#pragma unroll
  for (int ky = 0; ky < 3; ++ky) {
    int iy = h + ky - 1;
    rok[ky] = (iy >= 0 && iy < H);
    roff[ky] = iy * W + w - 1;
  }
#pragma unroll
  for (int kx = 0; kx < 3; ++kx) {
    int ix = w + kx - 1;
    cok[kx] = (ix >= 0 && ix < W);
  }
  __syncthreads();
  float a0 = 0.f, a1 = 0.f, a2 = 0.f;
  int ci0 = wv * 64;
  const float* ib = inL + ci0 * HW;
#pragma unroll 1
  for (int ci = ci0; ci < ci0 + 64; ++ci, ib += HW) {
    float v[9];
    load9(v, ib, rok, cok, roff);
    const float4* wr = w3s + ci * 9;
#pragma unroll
    for (int t9 = 0; t9 < 9; ++t9) {
      float4 wt = wr[t9];                  // broadcast ds_read_b128
      float vv = v[t9];
      a0 += vv * wt.x; a1 += vv * wt.y; a2 += vv * wt.z;
    }
  }
  red[wv][ln][0] = a0; red[wv][ln][1] = a1; red[wv][ln][2] = a2;
  __syncthreads();
  if (wv == 0 && valid) {
    int gbase = LV_AOFF[L] + pix * 3;
#pragma unroll
    for (int a = 0; a < 3; ++a) {
      float f = (red[0][ln][a] + red[1][ln][a]) + (red[2][ln][a] + red[3][ln][a]);
      f += fb32[a];
      logits32[gbase + a] = f;
      atomicAdd(&hist[sort32f(f) >> 16], 1u);
    }
  }
}

// ---------------- edge finder (with 2-bin safety margin) ----------------
__global__ __launch_bounds__(1024) void k_edge(const uint32_t* __restrict__ hist,
                                               uint32_t* __restrict__ cnts) {
  __shared__ uint32_t cs[1024];
  __shared__ uint32_t g_grp, g_suf;
  int t = threadIdx.x, wv = t >> 6, ln = t & 63;
#pragma unroll 4
  for (int r = 0; r < 64; ++r) {
    int g = r * 16 + wv;
    uint32_t x = hist[g * 64 + ln];
#pragma unroll
    for (int off = 32; off > 0; off >>= 1) x += __shfl_down(x, off);
    if (ln == 0) cs[g] = x;
  }
  __syncthreads();
  for (int off = 1; off < 1024; off <<= 1) {
    uint32_t v = cs[t] + ((t + off < 1024) ? cs[t + off] : 0u);
    __syncthreads();
    cs[t] = v;
    __syncthreads();
  }
  uint32_t sufnext = (t < 1023) ? cs[t + 1] : 0u;
  if (cs[t] >= PRE_NMS && sufnext < PRE_NMS) {   // unique t
    g_grp = (uint32_t)t;
    g_suf = sufnext;
  }
  __syncthreads();
  if (t < 64) {   // wave 0: refine edge within the winning 64-bin group
    uint32_t grp = g_grp, suf = g_suf;
    uint32_t x = hist[grp * 64 + t];
    uint32_t S = x;
#pragma unroll
    for (int off = 1; off < 64; off <<= 1) {
      uint32_t y = __shfl_down(S, off);
      if (t + off < 64) S += y;
    }
    unsigned long long mask = __ballot(suf + S >= PRE_NMS);
    int hi = 63 - (int)__clzll(mask);
    if (t == hi) {
      uint32_t e = grp * 64 + (uint32_t)hi;
      cnts[1] = (e > 2) ? e - 2 : 0;     // -2 bin margin: f32 superset of f64 top-k
    }
  }
}

// ---------------- pool compaction (f32 screen) ----------------
__global__ __launch_bounds__(256) void k_compact(const float* __restrict__ logits32,
                                                 uint32_t* __restrict__ cnts,
                                                 uint32_t* __restrict__ alist) {
  int i = blockIdx.x * 256 + threadIdx.x;
  if (i >= N_ANCH) return;
  if ((sort32f(logits32[i]) >> 16) >= cnts[1]) {
    uint32_t pos = atomicAdd(&cnts[0], 1u);
    if (pos < POOL_CAP) alist[pos] = (uint32_t)i;
  }
}

// ---------------- f64 refine: exact logit + deltas + sort key ----------------
__global__ __launch_bounds__(256) void k_refine(
    const float* __restrict__ p0, const float* __restrict__ p1,
    const float* __restrict__ p2, const float* __restrict__ p3,
    const float* __restrict__ p4,
    const double* __restrict__ Weff, const double* __restrict__ fb,
    const uint32_t* __restrict__ alist, const uint32_t* __restrict__ cnts,
    double* __restrict__ logits, double* __restrict__ deltas,
    uint64_t* __restrict__ pkey) {
  __shared__ double red[4][64][5];
  int tid = threadIdx.x, wv = tid >> 6, ln = tid & 63;
  int cnt = (int)cnts[0];
  if (cnt > POOL_CAP) cnt = POOL_CAP;
  int base = blockIdx.x * 64;
  if (base >= cnt) return;                 // uniform early-exit
  int slot = base + ln;
  if (slot >= cnt) slot = cnt - 1;         // dup tail (benign same-value writes)
  int gi = (int)alist[slot];
  int gpix = gi / 3, a = gi - gpix * 3;
  int L = 0;
  while (L < 4 && gpix >= GPOFF[L + 1]) ++L;
  int pix = gpix - GPOFF[L];
  const float* inL = (L == 0) ? p0 : (L == 1) ? p1 : (L == 2) ? p2 : (L == 3) ? p3 : p4;
  int H = LV_H[L], W = LV_W[L], HW = H * W;
  int h = pix / W, w = pix % W;
  bool rok[3], cok[3];
  int roff[3];
#pragma unroll
  for (int ky = 0; ky < 3; ++ky) {
    int iy = h + ky - 1;
    rok[ky] = (iy >= 0 && iy < H);
    roff[ky] = iy * W + w - 1;
  }
#pragma unroll
  for (int kx = 0; kx < 3; ++kx) {
    int ix = w + kx - 1;
    cok[kx] = (ix >= 0 && ix < W);
  }
  double sc = 0.0, d0 = 0.0, d1 = 0.0, d2 = 0.0, d3 = 0.0;
  int js = a, jd = 3 + 4 * a;
  int ci0 = wv * 64;
  const float* ib = inL + ci0 * HW;
#pragma unroll 1
  for (int ci = ci0; ci < ci0 + 64; ++ci, ib += HW) {
    float v[9];
    load9(v, ib, rok, cok, roff);
    const double* wr = Weff + ((size_t)ci * 144);
#pragma unroll
    for (int t9 = 0; t9 < 9; ++t9) {
      double vd = (double)v[t9];
      const double* wt = wr + t9 * 16;
      sc += vd * wt[js];
      d0 += vd * wt[jd + 0];
      d1 += vd * wt[jd + 1];
      d2 += vd * wt[jd + 2];
      d3 += vd * wt[jd + 3];
    }
  }
  red[wv][ln][0] = sc;
  red[wv][ln][1] = d0; red[wv][ln][2] = d1;
  red[wv][ln][3] = d2; red[wv][ln][4] = d3;
  __syncthreads();
  if (wv == 0) {
    double f[5];
#pragma unroll
    for (int j = 0; j < 5; ++j)
      f[j] = red[0][ln][j] + red[1][ln][j] + red[2][ln][j] + red[3][ln][j];
    double lg = f[0] + fb[js];
    logits[gi] = lg;
    deltas[gi * 4 + 0] = f[1] + fb[jd + 0];
    deltas[gi * 4 + 1] = f[2] + fb[jd + 1];
    deltas[gi * 4 + 2] = f[3] + fb[jd + 2];
    deltas[gi * 4 + 3] = f[4] + fb[jd + 3];
    // top-47 bits of sortable f64 logit; low 17 bits inverted index ->
    // rank-descending breaks score ties by ascending index (top_k semantics)
    pkey[slot] = (sort64(lg) & ~0x1FFFFull) | (uint64_t)(0x1FFFFu - (uint32_t)gi);
  }
}

// ---------------- 2D rank-by-counting: 32 i-tiles x 16 j-chunks ----------------
// rank32[e] += #{j in chunk : pkey[j] > pkey[e]}  (u32 atomics: exact, commutative)
__global__ __launch_bounds__(256) void k_rank_cnt(const uint32_t* __restrict__ cnts,
                                                  const uint64_t* __restrict__ pkey,
                                                  uint32_t* __restrict__ rank32) {
  __shared__ uint64_t lk[512];
  int t = threadIdx.x;
  int cnt = (int)cnts[0];
  if (cnt > POOL_CAP) cnt = POOL_CAP;
  int it = blockIdx.x >> 4, jc = blockIdx.x & 15;
  int e = it * 256 + t;
  int c0 = jc * 512;
  if (it * 256 >= cnt || c0 >= cnt) return;   // uniform early-exit
  int lim = cnt - c0; if (lim > 512) lim = 512;
  for (int i = t; i < 512; i += 256) lk[i] = (i < lim) ? pkey[c0 + i] : 0ull;
  __syncthreads();
  bool active = e < cnt;
  uint64_t mykey = active ? pkey[e] : ~0ull;   // ~0 counts nothing
  int r = 0;
#pragma unroll 8
  for (int j = 0; j < 512; ++j) r += (lk[j] > mykey) ? 1 : 0;
  if (active && r) atomicAdd(&rank32[e], (uint32_t)r);
}

// ---------------- scatter by rank + box decode ----------------
__global__ __launch_bounds__(256) void k_scatter(const uint32_t* __restrict__ cnts,
                                                 const uint64_t* __restrict__ pkey,
                                                 const uint32_t* __restrict__ rank32,
                                                 const double* __restrict__ logits,
                                                 const double* __restrict__ deltas,
                                                 const float* __restrict__ im_info,
                                                 double* __restrict__ ss,
                                                 double* __restrict__ sbx,
                                                 float4* __restrict__ bxf,
                                                 float* __restrict__ areaf) {
  int t = threadIdx.x;
  int cnt = (int)cnts[0];
  if (cnt > POOL_CAP) cnt = POOL_CAP;
  int e = blockIdx.x * 256 + t;
  if (blockIdx.x * 256 >= cnt) return;     // uniform
  if (e >= cnt) return;
  int rank = (int)rank32[e];
  if (rank >= PRE_NMS) return;
  uint64_t mykey = pkey[e];
  int gi = 0x1FFFF - (int)(mykey & 0x1FFFFull);
  int L = 0;
  while (L < 4 && gi >= LV_AOFF[L + 1]) ++L;
  int rel = gi - LV_AOFF[L];
  int pix = rel / 3, a = rel % 3;
  int W = LV_W[L];
  int h = pix / W, w = pix % W;
  double imW1 = (double)im_info[1] - 1.0;
  double imH1 = (double)im_info[0] - 1.0;
  double shx = (double)(w * LV_STRIDE[L]), shy = (double)(h * LV_STRIDE[L]);
  double ax1 = BASE_ANCH[L][a][0] + shx, ay1 = BASE_ANCH[L][a][1] + shy;
  double ax2 = BASE_ANCH[L][a][2] + shx, ay2 = BASE_ANCH[L][a][3] + shy;
  double dx = deltas[gi * 4 + 0], dy = deltas[gi * 4 + 1];
  double dw = deltas[gi * 4 + 2], dh = deltas[gi * 4 + 3];
  double wa = ax2 - ax1 + 1.0, ha = ay2 - ay1 + 1.0;
  double cx = ax1 + 0.5 * wa, cy = ay1 + 0.5 * ha;
  double pcx = dx * wa + cx, pcy = dy * ha + cy;
  double pw = exp(dw) * wa, ph = exp(dh) * ha;
  double x1 = fmin(fmax(pcx - 0.5 * pw, 0.0), imW1);
  double y1 = fmin(fmax(pcy - 0.5 * ph, 0.0), imH1);
  double x2 = fmin(fmax(pcx + 0.5 * pw, 0.0), imW1);
  double y2 = fmin(fmax(pcy + 0.5 * ph, 0.0), imH1);
  ss[rank] = 1.0 / (1.0 + exp(-logits[gi]));
  sbx[rank * 4 + 0] = x1; sbx[rank * 4 + 1] = y1;
  sbx[rank * 4 + 2] = x2; sbx[rank * 4 + 3] = y2;
  float4 bf;
  bf.x = (float)x1; bf.y = (float)y1; bf.z = (float)x2; bf.w = (float)y2;
  bxf[rank] = bf;
  areaf[rank] = (float)((x2 - x1 + 1.0) * (y2 - y1 + 1.0));
}

// ---------------- exact f64 IoU decision (reference semantics) ----------------
__device__ __forceinline__ bool iou_gt(const double* A, const double* B) {
  double areaA = (A[2] - A[0] + 1.0) * (A[3] - A[1] + 1.0);
  double areaB = (B[2] - B[0] + 1.0) * (B[3] - B[1] + 1.0);
  double xx1 = fmax(A[0], B[0]), yy1 = fmax(A[1], B[1]);
  double xx2 = fmin(A[2], B[2]), yy2 = fmin(A[3], B[3]);
  double iw = fmax(0.0, xx2 - xx1 + 1.0), ih = fmax(0.0, yy2 - yy1 + 1.0);
  double inter = iw * ih;
  return inter > 0.7 * (areaA + areaB - inter);
}

// ---------------- suppression matrix build (upper triangle) ----------------
// Sup[r][w] bit jj set  <=>  IoU(box r, box w*64+jj) > 0.7, for j > r.
// f32 prefilter with +-4.0 absolute margin on (inter - 0.7*union); f64 confirm
// in the gray zone -> decisions identical to pure f64. Rows/cols >= PRE_NMS
// may read unwritten (poisoned) staging rows; their bits are masked in k_scan.
__global__ __launch_bounds__(256) void k_build(const double* __restrict__ sbx,
                                               const float4* __restrict__ bxf,
                                               const float* __restrict__ areaf,
                                               uint64_t* __restrict__ Sup) {
  __shared__ float cbx[256][5];
  __shared__ float rbx[64][5];
  int blk = blockIdx.x;
  int rtile = blk / 24, ctile = blk % 24;   // 94 x 24
  int t = threadIdx.x, q = t >> 6, ln = t & 63;
  int r = rtile * 64 + ln;
  int w = ctile * 4 + q;                    // word 0..95
  {
    int c = ctile * 256 + t;
    float4 b;
    float ar;
    if (c < NMS_BLKS * 64) { b = bxf[c]; ar = areaf[c]; }
    else { b.x = b.y = b.z = b.w = 0.f; ar = 0.f; }
    cbx[t][0] = b.x; cbx[t][1] = b.y; cbx[t][2] = b.z; cbx[t][3] = b.w; cbx[t][4] = ar;
    if (t < 64) {
      int rr = rtile * 64 + t;
      float4 rb = bxf[rr];
      rbx[t][0] = rb.x; rbx[t][1] = rb.y; rbx[t][2] = rb.z; rbx[t][3] = rb.w;
      rbx[t][4] = areaf[rr];
    }
  }
  __syncthreads();
  uint64_t bits = 0ull;
  int j0 = w * 64;
  if (w < NMS_BLKS && j0 + 63 > r) {
    float ax1 = rbx[ln][0], ay1 = rbx[ln][1], ax2 = rbx[ln][2], ay2 = rbx[ln][3];
    float aar = rbx[ln][4];
#pragma unroll 4
    for (int jj = 0; jj < 64; ++jj) {
      int j = j0 + jj;
      if (j <= r) continue;
      int cl = q * 64 + jj;
      float iw = fminf(ax2, cbx[cl][2]) - fmaxf(ax1, cbx[cl][0]) + 1.f;
      float ih = fminf(ay2, cbx[cl][3]) - fmaxf(ay1, cbx[cl][1]) + 1.f;
      float inter = fmaxf(iw, 0.f) * fmaxf(ih, 0.f);
      float d = inter - 0.7f * (aar + cbx[cl][4] - inter);
      bool sup;
      if (d > 4.0f) sup = true;
      else if (d < -4.0f) sup = false;
      else sup = iou_gt(sbx + (size_t)r * 4, sbx + (size_t)j * 4);  // rare
      if (sup) bits |= 1ull << jj;
    }
  }
  Sup[(size_t)r * SUP_W + w] = bits;
}

// ---------------- bit-parallel greedy NMS scan ----------------
__global__ __launch_bounds__(256) void k_scan(const uint64_t* __restrict__ Sup,
                                              const double* __restrict__ ss,
                                              const double* __restrict__ sbx,
                                              float* __restrict__ out) {
  __shared__ uint16_t keep[POST_NMS];
  __shared__ uint64_t wpart[4];
  __shared__ uint64_t s_ext;
  __shared__ int kcnt;
  int t = threadIdx.x, wv = t >> 6, ln = t & 63;
  if (t == 0) kcnt = 0;
  __syncthreads();
  for (int b = 0; b < NMS_BLKS; ++b) {
    int base = b * 64;
    int K = kcnt;
    // OR of kept rows' word b  (K gathered u64 loads, spread over 256 threads)
    uint64_t m = 0ull;
    for (int p = t; p < K; p += 256) m |= Sup[(size_t)keep[p] * SUP_W + b];
#pragma unroll
    for (int off = 32; off > 0; off >>= 1) m |= __shfl_down(m, off);
    if (ln == 0) wpart[wv] = m;
    __syncthreads();
    if (t == 0) s_ext = wpart[0] | wpart[1] | wpart[2] | wpart[3];
    __syncthreads();
    if (wv == 0) {   // wave 0: ffs-driven serial scan (iterates kept only)
      uint64_t myrow = Sup[(size_t)(base + ln) * SUP_W + b] & ~((2ull << ln) - 1ull);
      uint64_t ext = s_ext;
      if (base + 63 >= PRE_NMS) {
        int v = PRE_NMS - base;                  // 48 for the tail block
        ext |= ~((1ull << v) - 1ull);
      }
      uint64_t avail = ~ext;
      uint64_t kp = 0ull;
      int K0 = kcnt, lim = POST_NMS - K0, nk = 0;
      while (avail && nk < lim) {
        int i2 = __ffsll((unsigned long long)avail) - 1;
        kp |= 1ull << i2;
        ++nk;
        uint64_t row = __shfl(myrow, i2);
        avail &= ~row;
        avail &= ~(1ull << i2);
      }
      if ((kp >> ln) & 1ull) {
        int pos = K0 + __popcll(kp & ((1ull << ln) - 1ull));
        keep[pos] = (uint16_t)(base + ln);
      }
      if (ln == 0) kcnt = K0 + nk;
    }
    __syncthreads();
    if (kcnt >= POST_NMS) break;
  }
  __syncthreads();
  int KF = kcnt;
  for (int r = t; r < POST_NMS; r += 256) {
    float* o = out + r * 6;
    if (r < KF) {
      int p = keep[r];
      o[0] = 0.f;
      o[1] = (float)sbx[p * 4 + 0];
      o[2] = (float)sbx[p * 4 + 1];
      o[3] = (float)sbx[p * 4 + 2];
      o[4] = (float)sbx[p * 4 + 3];
      o[5] = (float)ss[p];
    } else {
#pragma unroll
      for (int c = 0; c < 6; ++c) o[c] = 0.f;
    }
  }
}

// ---------------- host launch ----------------
extern "C" void kernel_launch(void* const* d_in, const int* in_sizes, int n_in,
                              void* d_out, int out_size, void* d_ws, size_t ws_size,
                              hipStream_t stream) {
  const float* p0 = (const float*)d_in[0];
  const float* p1 = (const float*)d_in[1];
  const float* p2 = (const float*)d_in[2];
  const float* p3 = (const float*)d_in[3];
  const float* p4 = (const float*)d_in[4];
  const float* im_info = (const float*)d_in[5];
  const float* cw = (const float*)d_in[6];
  const float* cb = (const float*)d_in[7];
  const float* sw = (const float*)d_in[8];
  const float* sb = (const float*)d_in[9];
  const float* bw = (const float*)d_in[10];
  const float* bb = (const float*)d_in[11];
  char* ws = (char*)d_ws;
  // ws layout (bytes):
  uint32_t* hist    = (uint32_t*)(ws + 0);         // 65536 u32 -> 262144
  uint32_t* cnts    = (uint32_t*)(ws + 262144);    // [0]=pool [1]=edge -> 262208
  double*   fb      = (double*)  (ws + 262208);    // 16 f64 -> 262336
  float*    fb32    = (float*)   (ws + 262336);    // 4 f32  -> 262352
  double*   logits  = (double*)  (ws + 262352);    // 106392 f64 -> 1113488
  double*   deltas  = (double*)  (ws + 1113488);   // 425568 f64 -> 4518032
  float*    logits32= (float*)   (ws + 4518032);   // 106392 f32 -> 4943600
  float4*   w3      = (float4*)  (ws + 4943600);   // 2304 float4 -> 4980464
  double*   Weff    = (double*)  (ws + 4980464);   // 2304*16 f64 -> 5275376
  double*   Wpart   = (double*)  (ws + 5275376);   // 16*2304*16 f64 -> 9993968
  uint32_t* alist   = (uint32_t*)(ws + 9993968);   // 8192 u32 -> 10026736
  double*   ssort   = (double*)  (ws + 10026736);  // 6016 f64 -> 10074864
  double*   sbx     = (double*)  (ws + 10074864);  // 6016*4 f64 -> 10267376
  float4*   bxf     = (float4*)  (ws + 10267376);  // 6016 float4 -> 10363632
  float*    areaf   = (float*)   (ws + 10363632);  // 6016 f32 -> 10387696
  uint64_t* Sup     = (uint64_t*)(ws + 10387696);  // 6016*96 u64 -> 15007984
  uint64_t* pkey    = (uint64_t*)(ws + 15007984);  // 8192 u64 -> 15073520
  uint32_t* rank32  = (uint32_t*)(ws + 15073520);  // 8192 u32 -> 15106288
  float* out = (float*)d_out;

  hipMemsetAsync(ws, 0, 262208, stream);             // hist + counters
  hipMemsetAsync(rank32, 0, 32768, stream);          // rank accumulators
  k_weff_part<<<144, 256, 0, stream>>>(cw, sw, bw, Wpart);
  k_weff_fin<<<10, 256, 0, stream>>>(Wpart, cb, sb, bb, sw, bw, Weff, fb, w3, fb32);
  k_fast<<<555, 256, 0, stream>>>(p0, p1, p2, p3, p4, w3, fb32, logits32, hist);
  k_edge<<<1, 1024, 0, stream>>>(hist, cnts);
  k_compact<<<416, 256, 0, stream>>>(logits32, cnts, alist);
  k_refine<<<128, 256, 0, stream>>>(p0, p1, p2, p3, p4, Weff, fb, alist, cnts,
                                    logits, deltas, pkey);
  k_rank_cnt<<<512, 256, 0, stream>>>(cnts, pkey, rank32);
  k_scatter<<<32, 256, 0, stream>>>(cnts, pkey, rank32, logits, deltas, im_info,
                                    ssort, sbx, bxf, areaf);
  k_build<<<94 * 24, 256, 0, stream>>>(sbx, bxf, areaf, Sup);
  k_scan<<<1, 256, 0, stream>>>(Sup, ssort, sbx, out);
}